// Round 5
// baseline (347.822 us; speedup 1.0000x reference)
//
#include <hip/hip_runtime.h>

// Kalman filter forward. out[b,v,t] (t>=1) = H m_t,
//   m_{t+1} = M_t m_t + G_t x[:,:,t],  M_t = F(I-K_t H), G_t = F K_t.
// K_t is batch-independent (P0 = I for all batches).
// Phase 1 (1 block): Riccati recursion, early stop at DARE convergence.
//   R5: S^-1 path = register-resident Gauss-Jordan on [S|HP] in ONE wave
//   (cols in VGPRs, pivot broadcast via v_readlane) -- zero barriers, ~3.5us,
//   run EVERY step (Newton + R^-1 machinery deleted; R4 showed 268 barrier
//   phases x ~0.9us dominate). 5 barrier phases + 1 wave-local GJ per step.
//   Epilogue builds M^2..M^4, M^kG, HM^k, HM^kG for phase-2 quad stepping.
// Phase 2 (128 blocks): transient single steps t<tc, then QUAD steps:
//   emits y_t..y_{t+3} and m_{t+4} from m_t -- 1 barrier per 4 timesteps.

#define SD 64
#define NV 32
#define TSZ 128
#define BSZ 128
#define TMAX 120                            // hard cap on Riccati steps

#define MG_STRIDE (SD*SD + SD*NV)           // 6144 floats per step: M then G
#define WS_PAIR (120*MG_STRIDE)             // quad-matrix block (27648 floats)
#define WS_TC   (WS_PAIR + 27648)           // int: converged step index
// pair block offsets (floats from WS_PAIR)
#define OFF_M2   0
#define OFF_M3   4096
#define OFF_M4   8192
#define OFF_MG   12288
#define OFF_M2G  14336
#define OFF_M3G  16384
#define OFF_HM   18432
#define OFF_HM2  20480
#define OFF_HM3  22528
#define OFF_HG   24576
#define OFF_HMG  25600
#define OFF_HM2G 26624

typedef __attribute__((ext_vector_type(8))) short bf16x8;
typedef __attribute__((ext_vector_type(4))) float f32x4;

// pack fp32 -> (bf16_hi << 16) | bf16_lo   (RNE both)
__device__ __forceinline__ unsigned packhl(float v) {
  unsigned b = __float_as_uint(v);
  unsigned hi = (b + 0x7FFFu + ((b >> 16) & 1u)) & 0xFFFF0000u;
  float lo = v - __uint_as_float(hi);
  unsigned lb = __float_as_uint(lo);
  unsigned lo16 = ((lb + 0x7FFFu + ((lb >> 16) & 1u)) >> 16);
  return hi | (lo16 & 0xFFFFu);
}

__device__ __forceinline__ float unpackf(unsigned u) {
  return __uint_as_float(u & 0xFFFF0000u) + __uint_as_float(u << 16);
}

__device__ __forceinline__ void frags_from(const unsigned* __restrict__ p,
                                           bf16x8& hi, bf16x8& lo) {
  uint4 a = *(const uint4*)p;
  uint4 b = *(const uint4*)(p + 4);
  unsigned u0=a.x,u1=a.y,u2=a.z,u3=a.w,u4=b.x,u5=b.y,u6=b.z,u7=b.w;
  hi[0]=(short)(u0>>16); hi[1]=(short)(u1>>16); hi[2]=(short)(u2>>16); hi[3]=(short)(u3>>16);
  hi[4]=(short)(u4>>16); hi[5]=(short)(u5>>16); hi[6]=(short)(u6>>16); hi[7]=(short)(u7>>16);
  lo[0]=(short)(u0&0xFFFFu); lo[1]=(short)(u1&0xFFFFu); lo[2]=(short)(u2&0xFFFFu); lo[3]=(short)(u3&0xFFFFu);
  lo[4]=(short)(u4&0xFFFFu); lo[5]=(short)(u5&0xFFFFu); lo[6]=(short)(u6&0xFFFFu); lo[7]=(short)(u7&0xFFFFu);
}

// c += A*B over 32 k-elements with split-bf16 (3 mfma, lo*lo dropped)
__device__ __forceinline__ f32x4 mfma3(const unsigned* __restrict__ ap,
                                       const unsigned* __restrict__ bp, f32x4 c) {
  bf16x8 ah, al, bh, bl;
  frags_from(ap, ah, al);
  frags_from(bp, bh, bl);
  c = __builtin_amdgcn_mfma_f32_16x16x32_bf16(ah, bh, c, 0, 0, 0);
  c = __builtin_amdgcn_mfma_f32_16x16x32_bf16(ah, bl, c, 0, 0, 0);
  c = __builtin_amdgcn_mfma_f32_16x16x32_bf16(al, bh, c, 0, 0, 0);
  return c;
}

__device__ __forceinline__ float rdlane(float v, int lane) {
  return __uint_as_float(
      (unsigned)__builtin_amdgcn_readlane((int)__float_as_uint(v), lane));
}

__launch_bounds__(256)
__global__ void kf_phase1(const float* __restrict__ Fg,
                          const float* __restrict__ Hg,
                          const float* __restrict__ Rg,
                          const float* __restrict__ Qg,
                          float* __restrict__ ws) {
  __shared__ unsigned Fb [64*68];    // F row-major; epilogue: M2 packed
  __shared__ unsigned Pb [64*68];    // P (sym: A+B^T src); epilogue: M packed
  __shared__ unsigned Hb [32*68];    // H row-major
  __shared__ unsigned Htb[64*36];    // H^T row-major (B^T-src for FK*H)
  __shared__ unsigned Krb[64*36];    // -K row-major; epilogue: MG^T (LD 68)
  __shared__ unsigned Ktb[32*68];    // K^T row-major; epilogue: G^T
  __shared__ unsigned FKb[64*36];    // -FK row-major
  __shared__ unsigned HPr[64*68];    // HP row-major (32 rows); epi: M2^T
  __shared__ unsigned PHt[64*36];    // (HP)^T row-major; epi: HM packed (LD 68)
  __shared__ __align__(16) float AugPool[6400]; // fp32 [S|HP] LD 100; alias Zbu
  __shared__ float wred[4];
  __shared__ int conv;

  float* Aug = AugPool;
  unsigned* Zbu = (unsigned*)AugPool;          // 64x68 u32 (S6->S7); epi: M^T

  const int tid = threadIdx.x;
  const int w = tid >> 6, lane = tid & 63, quad = lane >> 4, l16 = lane & 15;

  // ---- prep: pack F, H, H^T; P = I ----
  for (int s = tid; s < SD*SD; s += 256) {
    int i = s >> 6, j = s & 63;
    Fb[i*68 + j] = packhl(Fg[s]);
    Pb[i*68 + j] = packhl((i == j) ? 1.0f : 0.0f);
  }
  for (int s = tid; s < NV*SD; s += 256) {
    int v = s >> 6, j = s & 63;
    Hb[v*68 + j] = packhl(Hg[s]);
  }
  for (int s = tid; s < SD*NV; s += 256) {
    int j = s >> 5, v = s & 31;
    Htb[j*36 + v] = packhl(Hg[v*SD + j]);
  }
  __syncthreads();

  int tcv = TMAX - 1;

  for (int t = 0; t < TMAX; ++t) {
    float* Mws = ws + (size_t)t * MG_STRIDE;
    float* Gws = Mws + SD*SD;
    const bool chk = (t >= 3);
    float dmax = 0.0f;

    // S1: HP = H @ P (A=H, B^T-src=P sym) -> HPr, PHt, Aug cols [32:96)
    for (int tt = w; tt < 8; tt += 4) {
      const int m0 = (tt >> 2) << 4, n0 = (tt & 3) << 4;
      f32x4 c = {0.f, 0.f, 0.f, 0.f};
      c = mfma3(Hb + (m0+l16)*68 +      quad*8, Pb + (n0+l16)*68 +      quad*8, c);
      c = mfma3(Hb + (m0+l16)*68 + 32 + quad*8, Pb + (n0+l16)*68 + 32 + quad*8, c);
      const int cc = n0 + l16, r0 = m0 + quad*4;
      unsigned pk0 = packhl(c[0]), pk1 = packhl(c[1]), pk2 = packhl(c[2]), pk3 = packhl(c[3]);
      HPr[(r0+0)*68 + cc] = pk0;
      HPr[(r0+1)*68 + cc] = pk1;
      HPr[(r0+2)*68 + cc] = pk2;
      HPr[(r0+3)*68 + cc] = pk3;
      *(uint4*)(PHt + cc*36 + r0) = make_uint4(pk0, pk1, pk2, pk3);
      Aug[(r0+0)*100 + 32 + cc] = c[0];
      Aug[(r0+1)*100 + 32 + cc] = c[1];
      Aug[(r0+2)*100 + 32 + cc] = c[2];
      Aug[(r0+3)*100 + 32 + cc] = c[3];
    }
    __syncthreads();

    // S2: S = HP @ H^T + R -> Aug cols [0:32)
    {
      const int m0 = (w >> 1) << 4, n0 = (w & 1) << 4;
      const int r0 = m0 + quad*4, cc = n0 + l16;
      f32x4 c;
      c[0] = Rg[(r0+0)*NV + cc];
      c[1] = Rg[(r0+1)*NV + cc];
      c[2] = Rg[(r0+2)*NV + cc];
      c[3] = Rg[(r0+3)*NV + cc];
      c = mfma3(HPr + (m0+l16)*68 +      quad*8, Hb + (n0+l16)*68 +      quad*8, c);
      c = mfma3(HPr + (m0+l16)*68 + 32 + quad*8, Hb + (n0+l16)*68 + 32 + quad*8, c);
      Aug[(r0+0)*100 + cc] = c[0];
      Aug[(r0+1)*100 + cc] = c[1];
      Aug[(r0+2)*100 + cc] = c[2];
      Aug[(r0+3)*100 + cc] = c[3];
    }
    __syncthreads();

    // S3: register-GJ on [S | HP] in wave 0 (SPD, no pivoting, no barriers).
    // lane l owns col l (colA) and col 64+l for l<32 (colB).
    // Result K^T = S^-1 HP: lane writes K^T col (l+32)&63.
    if (tid < 64) {
      const int l = tid;
      float colA[32], colB[32];
      const int cbi = (l < 32) ? (64 + l) : 64;   // clamp (lanes>=32 unused)
#pragma unroll
      for (int r = 0; r < 32; ++r) {
        colA[r] = Aug[r*100 + l];
        colB[r] = Aug[r*100 + cbi];
      }
#pragma unroll
      for (int p = 0; p < 32; ++p) {
        const float piv = rdlane(colA[p], p);
        const float inv = 1.0f / piv;
        const float rpA = colA[p] * inv;
        const float rpB = colB[p] * inv;
#pragma unroll
        for (int r = 0; r < 32; ++r) {
          if (r == p) continue;
          const float f = rdlane(colA[r], p);
          colA[r] -= f * rpA;
          colB[r] -= f * rpB;
        }
        colA[p] = rpA;
        colB[p] = rpB;
      }
      const int c = (l + 32) & 63;
#pragma unroll
      for (int r = 0; r < 32; ++r) {
        const float kv = (l < 32) ? colB[r] : colA[r];
        Ktb[r*68 + c] = packhl(kv);
        Krb[c*36 + r] = packhl(-kv);
      }
    }
    __syncthreads();

    // S5 || S8:  Pu = P - K*HP (16 tiles) || FK = F*K, G_t out (8 tiles)
    for (int tt = w; tt < 24; tt += 4) {
      if (tt < 16) {
        const int m0 = (tt >> 2) << 4, n0 = (tt & 3) << 4;
        const int r0 = m0 + quad*4, cc = n0 + l16;
        f32x4 c;
        c[0] = unpackf(Pb[(r0+0)*68 + cc]);
        c[1] = unpackf(Pb[(r0+1)*68 + cc]);
        c[2] = unpackf(Pb[(r0+2)*68 + cc]);
        c[3] = unpackf(Pb[(r0+3)*68 + cc]);
        c = mfma3(Krb + (m0+l16)*36 + quad*8, PHt + (n0+l16)*36 + quad*8, c);
        Pb[(r0+0)*68 + cc] = packhl(c[0]);
        Pb[(r0+1)*68 + cc] = packhl(c[1]);
        Pb[(r0+2)*68 + cc] = packhl(c[2]);
        Pb[(r0+3)*68 + cc] = packhl(c[3]);
      } else {
        const int ss = tt - 16;
        const int m0 = (ss >> 1) << 4, n0 = (ss & 1) << 4;
        f32x4 c = {0.f, 0.f, 0.f, 0.f};
        c = mfma3(Fb + (m0+l16)*68 +      quad*8, Ktb + (n0+l16)*68 +      quad*8, c);
        c = mfma3(Fb + (m0+l16)*68 + 32 + quad*8, Ktb + (n0+l16)*68 + 32 + quad*8, c);
        const int r0 = m0 + quad*4, cc = n0 + l16;
#pragma unroll
        for (int g = 0; g < 4; ++g) {
          float gv = c[g];
          Gws[(r0+g)*NV + cc] = gv;
          FKb[(r0+g)*36 + cc] = packhl(-gv);
          if (chk) {
            float o = *(Gws - MG_STRIDE + (r0+g)*NV + cc);
            dmax = fmaxf(dmax, fabsf(gv - o));
          }
        }
      }
    }
    __syncthreads();

    // S6 || S9:  Z = F*Pu -> Zbu (16) || M = F - FK*H -> ws (16)
    for (int tt = w; tt < 32; tt += 4) {
      if (tt < 16) {
        const int m0 = (tt >> 2) << 4, n0 = (tt & 3) << 4;
        f32x4 c = {0.f, 0.f, 0.f, 0.f};
        c = mfma3(Fb + (m0+l16)*68 +      quad*8, Pb + (n0+l16)*68 +      quad*8, c);
        c = mfma3(Fb + (m0+l16)*68 + 32 + quad*8, Pb + (n0+l16)*68 + 32 + quad*8, c);
        const int r0 = m0 + quad*4, cc = n0 + l16;
        Zbu[(r0+0)*68 + cc] = packhl(c[0]);
        Zbu[(r0+1)*68 + cc] = packhl(c[1]);
        Zbu[(r0+2)*68 + cc] = packhl(c[2]);
        Zbu[(r0+3)*68 + cc] = packhl(c[3]);
      } else {
        const int ss = tt - 16;
        const int m0 = (ss >> 2) << 4, n0 = (ss & 3) << 4;
        const int r0 = m0 + quad*4, cc = n0 + l16;
        f32x4 c;
        c[0] = Fg[(r0+0)*SD + cc];
        c[1] = Fg[(r0+1)*SD + cc];
        c[2] = Fg[(r0+2)*SD + cc];
        c[3] = Fg[(r0+3)*SD + cc];
        c = mfma3(FKb + (m0+l16)*36 + quad*8, Htb + (n0+l16)*36 + quad*8, c);
#pragma unroll
        for (int g = 0; g < 4; ++g) {
          float mv = c[g];
          Mws[(r0+g)*SD + cc] = mv;
          if (chk) {
            float o = *(Mws - MG_STRIDE + (r0+g)*SD + cc);
            dmax = fmaxf(dmax, fabsf(mv - o));
          }
        }
      }
    }
    __syncthreads();

    // S7: P = Z*F^T + Q  (B^T-src = F row-major)
    for (int tt = w; tt < 16; tt += 4) {
      const int m0 = (tt >> 2) << 4, n0 = (tt & 3) << 4;
      const int r0 = m0 + quad*4, cc = n0 + l16;
      f32x4 c;
      c[0] = Qg[(r0+0)*SD + cc];
      c[1] = Qg[(r0+1)*SD + cc];
      c[2] = Qg[(r0+2)*SD + cc];
      c[3] = Qg[(r0+3)*SD + cc];
      c = mfma3(Zbu + (m0+l16)*68 +      quad*8, Fb + (n0+l16)*68 +      quad*8, c);
      c = mfma3(Zbu + (m0+l16)*68 + 32 + quad*8, Fb + (n0+l16)*68 + 32 + quad*8, c);
      Pb[(r0+0)*68 + cc] = packhl(c[0]);
      Pb[(r0+1)*68 + cc] = packhl(c[1]);
      Pb[(r0+2)*68 + cc] = packhl(c[2]);
      Pb[(r0+3)*68 + cc] = packhl(c[3]);
    }

    if (chk) {
#pragma unroll
      for (int off = 32; off >= 1; off >>= 1)
        dmax = fmaxf(dmax, __shfl_xor(dmax, off));
      if ((tid & 63) == 0) wred[tid >> 6] = dmax;
    }
    __syncthreads();
    if (chk) {
      if (tid == 0)
        conv = (fmaxf(fmaxf(wred[0], wred[1]), fmaxf(wred[2], wred[3])) < 1e-4f) ? 1 : 0;
      __syncthreads();
      if (conv) { tcv = t; break; }
    }
  }
  if (tid == 0) ((int*)ws)[WS_TC] = tcv;

  // ---- epilogue: quad matrices of the converged system ----
  {
    const float* Mf = ws + (size_t)tcv * MG_STRIDE;
    const float* Gf = Mf + SD*SD;
    unsigned* Mp  = Pb;    // M packed row-major
    unsigned* Mtp = Zbu;   // M^T packed
    unsigned* Gtp = Ktb;   // G^T packed
    for (int s = tid; s < SD*SD; s += 256) {
      int i = s >> 6, j = s & 63;
      unsigned pk = packhl(Mf[s]);
      Mp[i*68 + j] = pk;
      Mtp[j*68 + i] = pk;
    }
    for (int s = tid; s < SD*NV; s += 256) {
      int i = s >> 5, v = s & 31;
      Gtp[v*68 + i] = packhl(Gf[s]);
    }
    __syncthreads();

    float* M2o = ws + WS_PAIR;
    unsigned* M2p  = Fb;   // M^2 packed row-major
    unsigned* M2tp = HPr;  // (M^2)^T packed
    unsigned* MGtp = Krb;  // (MG)^T packed (LD 68, 32 rows)
    unsigned* HMp  = PHt;  // HM packed row-major (LD 68, 32 rows)

    // E0: M2=M*M, M2^T=M^T*M^T, MG=M*G, HM=H*M, HG=H*G
    for (int tt = w; tt < 52; tt += 4) {
      if (tt < 16) {                           // M2 (and fp32 out)
        const int m0 = (tt >> 2) << 4, n0 = (tt & 3) << 4;
        f32x4 c = {0.f, 0.f, 0.f, 0.f};
        c = mfma3(Mp + (m0+l16)*68 +      quad*8, Mtp + (n0+l16)*68 +      quad*8, c);
        c = mfma3(Mp + (m0+l16)*68 + 32 + quad*8, Mtp + (n0+l16)*68 + 32 + quad*8, c);
        const int r0 = m0 + quad*4, cc = n0 + l16;
#pragma unroll
        for (int g = 0; g < 4; ++g) {
          M2o[OFF_M2 + (r0+g)*SD + cc] = c[g];
          M2p[(r0+g)*68 + cc] = packhl(c[g]);
        }
      } else if (tt < 32) {                    // M2^T = M^T * M^T
        const int ss = tt - 16;
        const int m0 = (ss >> 2) << 4, n0 = (ss & 3) << 4;
        f32x4 c = {0.f, 0.f, 0.f, 0.f};
        c = mfma3(Mtp + (m0+l16)*68 +      quad*8, Mp + (n0+l16)*68 +      quad*8, c);
        c = mfma3(Mtp + (m0+l16)*68 + 32 + quad*8, Mp + (n0+l16)*68 + 32 + quad*8, c);
        const int r0 = m0 + quad*4, cc = n0 + l16;
#pragma unroll
        for (int g = 0; g < 4; ++g) M2tp[(r0+g)*68 + cc] = packhl(c[g]);
      } else if (tt < 40) {                    // MG (fp32 + (MG)^T packed)
        const int ss = tt - 32;
        const int m0 = (ss >> 1) << 4, n0 = (ss & 1) << 4;
        f32x4 c = {0.f, 0.f, 0.f, 0.f};
        c = mfma3(Mp + (m0+l16)*68 +      quad*8, Gtp + (n0+l16)*68 +      quad*8, c);
        c = mfma3(Mp + (m0+l16)*68 + 32 + quad*8, Gtp + (n0+l16)*68 + 32 + quad*8, c);
        const int r0 = m0 + quad*4, cc = n0 + l16;
#pragma unroll
        for (int g = 0; g < 4; ++g) M2o[OFF_MG + (r0+g)*NV + cc] = c[g];
        *(uint4*)(MGtp + cc*68 + r0) =
            make_uint4(packhl(c[0]), packhl(c[1]), packhl(c[2]), packhl(c[3]));
      } else if (tt < 48) {                    // HM (fp32 + packed row-major)
        const int ss = tt - 40;
        const int m0 = (ss >> 2) << 4, n0 = (ss & 3) << 4;
        f32x4 c = {0.f, 0.f, 0.f, 0.f};
        c = mfma3(Hb + (m0+l16)*68 +      quad*8, Mtp + (n0+l16)*68 +      quad*8, c);
        c = mfma3(Hb + (m0+l16)*68 + 32 + quad*8, Mtp + (n0+l16)*68 + 32 + quad*8, c);
        const int r0 = m0 + quad*4, cc = n0 + l16;
#pragma unroll
        for (int g = 0; g < 4; ++g) {
          M2o[OFF_HM + (r0+g)*SD + cc] = c[g];
          HMp[(r0+g)*68 + cc] = packhl(c[g]);
        }
      } else {                                 // HG (fp32)
        const int ss = tt - 48;
        const int m0 = (ss >> 1) << 4, n0 = (ss & 1) << 4;
        f32x4 c = {0.f, 0.f, 0.f, 0.f};
        c = mfma3(Hb + (m0+l16)*68 +      quad*8, Gtp + (n0+l16)*68 +      quad*8, c);
        c = mfma3(Hb + (m0+l16)*68 + 32 + quad*8, Gtp + (n0+l16)*68 + 32 + quad*8, c);
        const int r0 = m0 + quad*4, cc = n0 + l16;
#pragma unroll
        for (int g = 0; g < 4; ++g) M2o[OFF_HG + (r0+g)*NV + cc] = c[g];
      }
    }
    __syncthreads();

    // E1: M3=M2*M, M4=M2*M2, M2G=M2*G, M3G=M2*MG, HM2=HM*M, HM3=HM*M2,
    //     HMG=HM*G, HM2G=HM*MG  (all fp32-out only)
    for (int tt = w; tt < 72; tt += 4) {
      if (tt < 16) {                           // M3
        const int m0 = (tt >> 2) << 4, n0 = (tt & 3) << 4;
        f32x4 c = {0.f, 0.f, 0.f, 0.f};
        c = mfma3(M2p + (m0+l16)*68 +      quad*8, Mtp + (n0+l16)*68 +      quad*8, c);
        c = mfma3(M2p + (m0+l16)*68 + 32 + quad*8, Mtp + (n0+l16)*68 + 32 + quad*8, c);
        const int r0 = m0 + quad*4, cc = n0 + l16;
#pragma unroll
        for (int g = 0; g < 4; ++g) M2o[OFF_M3 + (r0+g)*SD + cc] = c[g];
      } else if (tt < 32) {                    // M4
        const int ss = tt - 16;
        const int m0 = (ss >> 2) << 4, n0 = (ss & 3) << 4;
        f32x4 c = {0.f, 0.f, 0.f, 0.f};
        c = mfma3(M2p + (m0+l16)*68 +      quad*8, M2tp + (n0+l16)*68 +      quad*8, c);
        c = mfma3(M2p + (m0+l16)*68 + 32 + quad*8, M2tp + (n0+l16)*68 + 32 + quad*8, c);
        const int r0 = m0 + quad*4, cc = n0 + l16;
#pragma unroll
        for (int g = 0; g < 4; ++g) M2o[OFF_M4 + (r0+g)*SD + cc] = c[g];
      } else if (tt < 40) {                    // M2G
        const int ss = tt - 32;
        const int m0 = (ss >> 1) << 4, n0 = (ss & 1) << 4;
        f32x4 c = {0.f, 0.f, 0.f, 0.f};
        c = mfma3(M2p + (m0+l16)*68 +      quad*8, Gtp + (n0+l16)*68 +      quad*8, c);
        c = mfma3(M2p + (m0+l16)*68 + 32 + quad*8, Gtp + (n0+l16)*68 + 32 + quad*8, c);
        const int r0 = m0 + quad*4, cc = n0 + l16;
#pragma unroll
        for (int g = 0; g < 4; ++g) M2o[OFF_M2G + (r0+g)*NV + cc] = c[g];
      } else if (tt < 48) {                    // M3G = M2 * MG
        const int ss = tt - 40;
        const int m0 = (ss >> 1) << 4, n0 = (ss & 1) << 4;
        f32x4 c = {0.f, 0.f, 0.f, 0.f};
        c = mfma3(M2p + (m0+l16)*68 +      quad*8, MGtp + (n0+l16)*68 +      quad*8, c);
        c = mfma3(M2p + (m0+l16)*68 + 32 + quad*8, MGtp + (n0+l16)*68 + 32 + quad*8, c);
        const int r0 = m0 + quad*4, cc = n0 + l16;
#pragma unroll
        for (int g = 0; g < 4; ++g) M2o[OFF_M3G + (r0+g)*NV + cc] = c[g];
      } else if (tt < 56) {                    // HM2 = HM * M
        const int ss = tt - 48;
        const int m0 = (ss >> 2) << 4, n0 = (ss & 3) << 4;
        f32x4 c = {0.f, 0.f, 0.f, 0.f};
        c = mfma3(HMp + (m0+l16)*68 +      quad*8, Mtp + (n0+l16)*68 +      quad*8, c);
        c = mfma3(HMp + (m0+l16)*68 + 32 + quad*8, Mtp + (n0+l16)*68 + 32 + quad*8, c);
        const int r0 = m0 + quad*4, cc = n0 + l16;
#pragma unroll
        for (int g = 0; g < 4; ++g) M2o[OFF_HM2 + (r0+g)*SD + cc] = c[g];
      } else if (tt < 64) {                    // HM3 = HM * M2
        const int ss = tt - 56;
        const int m0 = (ss >> 2) << 4, n0 = (ss & 3) << 4;
        f32x4 c = {0.f, 0.f, 0.f, 0.f};
        c = mfma3(HMp + (m0+l16)*68 +      quad*8, M2tp + (n0+l16)*68 +      quad*8, c);
        c = mfma3(HMp + (m0+l16)*68 + 32 + quad*8, M2tp + (n0+l16)*68 + 32 + quad*8, c);
        const int r0 = m0 + quad*4, cc = n0 + l16;
#pragma unroll
        for (int g = 0; g < 4; ++g) M2o[OFF_HM3 + (r0+g)*SD + cc] = c[g];
      } else if (tt < 68) {                    // HMG = HM * G
        const int ss = tt - 64;
        const int m0 = (ss >> 1) << 4, n0 = (ss & 1) << 4;
        f32x4 c = {0.f, 0.f, 0.f, 0.f};
        c = mfma3(HMp + (m0+l16)*68 +      quad*8, Gtp + (n0+l16)*68 +      quad*8, c);
        c = mfma3(HMp + (m0+l16)*68 + 32 + quad*8, Gtp + (n0+l16)*68 + 32 + quad*8, c);
        const int r0 = m0 + quad*4, cc = n0 + l16;
#pragma unroll
        for (int g = 0; g < 4; ++g) M2o[OFF_HMG + (r0+g)*NV + cc] = c[g];
      } else {                                 // HM2G = HM * MG
        const int ss = tt - 68;
        const int m0 = (ss >> 1) << 4, n0 = (ss & 1) << 4;
        f32x4 c = {0.f, 0.f, 0.f, 0.f};
        c = mfma3(HMp + (m0+l16)*68 +      quad*8, MGtp + (n0+l16)*68 +      quad*8, c);
        c = mfma3(HMp + (m0+l16)*68 + 32 + quad*8, MGtp + (n0+l16)*68 + 32 + quad*8, c);
        const int r0 = m0 + quad*4, cc = n0 + l16;
#pragma unroll
        for (int g = 0; g < 4; ++g) M2o[OFF_HM2G + (r0+g)*NV + cc] = c[g];
      }
    }
  }
}

__launch_bounds__(256)
__global__ void kf_phase2(const float* __restrict__ x,
                          const float* __restrict__ Hg,
                          const float* __restrict__ ws,
                          float* __restrict__ out) {
  __shared__ __align__(16) float Hs2[NV*65];
  __shared__ __align__(16) float xt[132*36];   // rows 128..131 zero-padded
  __shared__ __align__(16) float yb[NV*129];
  __shared__ __align__(16) float mbuf[2*SD];
  __shared__ __align__(16) float M4s [SD*68];
  __shared__ __align__(16) float M3Gs[SD*36];
  __shared__ __align__(16) float M2Gs[SD*36];
  __shared__ __align__(16) float MGs [SD*36];
  __shared__ __align__(16) float Gs  [SD*36];
  __shared__ __align__(16) float HMs [NV*68];
  __shared__ __align__(16) float HM2s[NV*68];
  __shared__ __align__(16) float HM3s[NV*68];
  __shared__ __align__(16) float HGs [NV*36];
  __shared__ __align__(16) float HMGs[NV*36];
  __shared__ __align__(16) float HM2Gs[NV*36];
  const int tid = threadIdx.x, b = blockIdx.x;

  const int tc = ((const int*)ws)[WS_TC];
  const float* P = ws + WS_PAIR;
  const float* Gf = ws + (size_t)tc * MG_STRIDE + SD*SD;

  for (int s = tid; s < NV*SD; s += 256) {
    int v = s >> 6, j = s & 63;
    Hs2[v*65 + j] = Hg[s];
    HMs [v*68 + j] = P[OFF_HM  + s];
    HM2s[v*68 + j] = P[OFF_HM2 + s];
    HM3s[v*68 + j] = P[OFF_HM3 + s];
  }
  for (int s = tid; s < SD*SD; s += 256) M4s[(s>>6)*68 + (s&63)] = P[OFF_M4 + s];
  for (int s = tid; s < SD*NV; s += 256) {
    int i = s >> 5, v = s & 31;
    M3Gs[i*36 + v] = P[OFF_M3G + s];
    M2Gs[i*36 + v] = P[OFF_M2G + s];
    MGs [i*36 + v] = P[OFF_MG  + s];
    Gs  [i*36 + v] = Gf[s];
  }
  for (int s = tid; s < NV*NV; s += 256) {
    int v = s >> 5, u = s & 31;
    HGs  [v*36 + u] = P[OFF_HG   + s];
    HMGs [v*36 + u] = P[OFF_HMG  + s];
    HM2Gs[v*36 + u] = P[OFF_HM2G + s];
  }
  for (int s = tid; s < 4*36; s += 256) xt[128*36 + s] = 0.0f;   // pad
  for (int s = tid; s < NV*TSZ; s += 256) {
    int v = s >> 7, t = s & 127;
    xt[t*36 + v] = x[(size_t)b*NV*TSZ + s];
  }
  if (tid < NV) yb[tid*129] = 0.0f;
  if (tid < 2*SD) mbuf[tid] = 0.0f;
  __syncthreads();

  const int i = tid >> 2, p4 = tid & 3;        // m rows: 4 threads per row
  const int v = tid >> 3, p8 = tid & 7;        // y rows: 8 threads per row
  int cb = 0;

  // ---- transient: single steps t = 0..tc-1 (coeffs from global ws) ----
  for (int t = 0; t < tc; ++t) {
    const float* Mt = ws + (size_t)t * MG_STRIDE;
    const float* Gt = Mt + SD*SD;
    const float* cur = mbuf + cb * SD;
    float*       nxt = mbuf + (cb ^ 1) * SD;

    float acc = 0.0f;
    {
      const int j0 = p4 * 16;
#pragma unroll
      for (int c = 0; c < 16; c += 4) {
        float4 mm = *(const float4*)(Mt + i*SD + j0 + c);
        float4 vv = *(const float4*)(cur + j0 + c);
        acc += mm.x*vv.x + mm.y*vv.y + mm.z*vv.z + mm.w*vv.w;
      }
      const int v0 = p4 * 8;
#pragma unroll
      for (int c = 0; c < 8; c += 4) {
        float4 gg = *(const float4*)(Gt + i*NV + v0 + c);
        float4 oo = *(const float4*)(xt + t*36 + v0 + c);
        acc += gg.x*oo.x + gg.y*oo.y + gg.z*oo.z + gg.w*oo.w;
      }
    }
    acc += __shfl_xor(acc, 1);
    acc += __shfl_xor(acc, 2);

    if (t >= 1) {
      float ys = 0.0f;
#pragma unroll
      for (int j = 0; j < 8; ++j)
        ys += Hs2[v*65 + p8*8 + j] * cur[p8*8 + j];
      ys += __shfl_xor(ys, 1);
      ys += __shfl_xor(ys, 2);
      ys += __shfl_xor(ys, 4);
      if (p8 == 0) yb[v*129 + t] = ys;
    }
    if (p4 == 0) nxt[i] = acc;
    __syncthreads();
    cb ^= 1;
  }

  // ---- quad steps: y_t..y_{t+3}, m_{t+4} from m_t; 1 barrier / 4 steps ----
  for (int t = tc; t < TSZ; t += 4) {
    const float* cur = mbuf + cb * SD;
    float*       nxt = mbuf + (cb ^ 1) * SD;
    const float* o0 = xt + t*36;
    const float* o1 = o0 + 36;
    const float* o2 = o1 + 36;
    const float* o3 = o2 + 36;

    // ---- y block (v, p8) ----
    {
      const int j8 = p8 * 8, j4 = p8 * 4;
      float y0 = 0.f, y1 = 0.f, y2 = 0.f, y3 = 0.f;
#pragma unroll
      for (int c = 0; c < 8; c += 4) {
        float4 vv = *(const float4*)(cur + j8 + c);
        float4 h0 = *(const float4*)(Hs2 + v*65 + j8 + c);
        float4 h1 = *(const float4*)(HMs + v*68 + j8 + c);
        float4 h2 = *(const float4*)(HM2s + v*68 + j8 + c);
        float4 h3 = *(const float4*)(HM3s + v*68 + j8 + c);
        y0 += h0.x*vv.x + h0.y*vv.y + h0.z*vv.z + h0.w*vv.w;
        y1 += h1.x*vv.x + h1.y*vv.y + h1.z*vv.z + h1.w*vv.w;
        y2 += h2.x*vv.x + h2.y*vv.y + h2.z*vv.z + h2.w*vv.w;
        y3 += h3.x*vv.x + h3.y*vv.y + h3.z*vv.z + h3.w*vv.w;
      }
      {
        float4 a = *(const float4*)(HGs + v*36 + j4);
        float4 bq = *(const float4*)(HMGs + v*36 + j4);
        float4 cq = *(const float4*)(HM2Gs + v*36 + j4);
        float4 q0 = *(const float4*)(o0 + j4);
        float4 q1 = *(const float4*)(o1 + j4);
        float4 q2 = *(const float4*)(o2 + j4);
        y1 += a.x*q0.x + a.y*q0.y + a.z*q0.z + a.w*q0.w;
        y2 += bq.x*q0.x + bq.y*q0.y + bq.z*q0.z + bq.w*q0.w
            + a.x*q1.x + a.y*q1.y + a.z*q1.z + a.w*q1.w;
        y3 += cq.x*q0.x + cq.y*q0.y + cq.z*q0.z + cq.w*q0.w
            + bq.x*q1.x + bq.y*q1.y + bq.z*q1.z + bq.w*q1.w
            + a.x*q2.x + a.y*q2.y + a.z*q2.z + a.w*q2.w;
      }
#pragma unroll
      for (int off = 1; off <= 4; off <<= 1) {
        y0 += __shfl_xor(y0, off);
        y1 += __shfl_xor(y1, off);
        y2 += __shfl_xor(y2, off);
        y3 += __shfl_xor(y3, off);
      }
      if (p8 == 0) {
        yb[v*129 + t] = y0;
        if (t + 1 < TSZ) yb[v*129 + t + 1] = y1;
        if (t + 2 < TSZ) yb[v*129 + t + 2] = y2;
        if (t + 3 < TSZ) yb[v*129 + t + 3] = y3;
      }
    }

    // ---- m block (i, p4): m_{t+4} = M4 m + M3G o0 + M2G o1 + MG o2 + G o3 --
    {
      float acc = 0.0f;
      const int j0 = p4 * 16;
#pragma unroll
      for (int c = 0; c < 16; c += 4) {
        float4 mm = *(const float4*)(M4s + i*68 + j0 + c);
        float4 vv = *(const float4*)(cur + j0 + c);
        acc += mm.x*vv.x + mm.y*vv.y + mm.z*vv.z + mm.w*vv.w;
      }
      const int v0 = p4 * 8;
#pragma unroll
      for (int c = 0; c < 8; c += 4) {
        float4 g3 = *(const float4*)(M3Gs + i*36 + v0 + c);
        float4 g2 = *(const float4*)(M2Gs + i*36 + v0 + c);
        float4 g1 = *(const float4*)(MGs + i*36 + v0 + c);
        float4 g0 = *(const float4*)(Gs + i*36 + v0 + c);
        float4 q0 = *(const float4*)(o0 + v0 + c);
        float4 q1 = *(const float4*)(o1 + v0 + c);
        float4 q2 = *(const float4*)(o2 + v0 + c);
        float4 q3 = *(const float4*)(o3 + v0 + c);
        acc += g3.x*q0.x + g3.y*q0.y + g3.z*q0.z + g3.w*q0.w;
        acc += g2.x*q1.x + g2.y*q1.y + g2.z*q1.z + g2.w*q1.w;
        acc += g1.x*q2.x + g1.y*q2.y + g1.z*q2.z + g1.w*q2.w;
        acc += g0.x*q3.x + g0.y*q3.y + g0.z*q3.z + g0.w*q3.w;
      }
      acc += __shfl_xor(acc, 1);
      acc += __shfl_xor(acc, 2);
      if (p4 == 0) nxt[i] = acc;
    }
    __syncthreads();
    cb ^= 1;
  }

  for (int s = tid; s < NV*TSZ; s += 256)
    out[(size_t)b*NV*TSZ + s] = yb[(s>>7)*129 + (s&127)];
}

extern "C" void kernel_launch(void* const* d_in, const int* in_sizes, int n_in,
                              void* d_out, int out_size, void* d_ws, size_t ws_size,
                              hipStream_t stream) {
  const float* x = (const float*)d_in[0];
  const float* F = (const float*)d_in[1];
  const float* H = (const float*)d_in[2];
  const float* R = (const float*)d_in[3];
  const float* Q = (const float*)d_in[4];
  float* out = (float*)d_out;
  float* ws  = (float*)d_ws;   // ~3.06 MB used

  hipLaunchKernelGGL(kf_phase1, dim3(1), dim3(256), 0, stream, F, H, R, Q, ws);
  hipLaunchKernelGGL(kf_phase2, dim3(BSZ), dim3(256), 0, stream, x, H, ws, out);
}

// Round 6
// 239.584 us; speedup vs baseline: 1.4518x; 1.4518x over previous
//
#include <hip/hip_runtime.h>

// Kalman filter forward. out[b,v,t] (t>=1) = H m_t,
//   m_{t+1} = M_t m_t + G_t x[:,:,t],  M_t = F(I-K_t H), G_t = F K_t.
// K_t is batch-independent (P0 = I). Phase 1 (1 block, 512 thr): Riccati
// recursion restructured to a 4-barrier step using P symmetry:
//   A: Y=HP, W=FP      B: S=YH^T+R, V=WH^T, T=WF^T
//   GJ (1 wave, regs): [S|V^T] -> G = V S^-1 (rcp+NR, G-convergence in-wave)
//   C: M=F-GH -> ws,   P' = T - G V^T + Q
// R5 post-mortem: phase1 is latency-bound (1 wave/SIMD, div chains); this
// cuts barrier phases ~70->~44, GJ critical path ~2x, and runs 2 waves/SIMD.
// Phase 2 (128 blocks): transient single steps then quad steps (unchanged).

#define SD 64
#define NV 32
#define TSZ 128
#define BSZ 128
#define TMAX 120

#define MG_STRIDE (SD*SD + SD*NV)           // 6144 floats per step: M then G
#define WS_PAIR (120*MG_STRIDE)             // quad-matrix block (27648 floats)
#define WS_TC   (WS_PAIR + 27648)           // int: converged step index
#define OFF_M2   0
#define OFF_M3   4096
#define OFF_M4   8192
#define OFF_MG   12288
#define OFF_M2G  14336
#define OFF_M3G  16384
#define OFF_HM   18432
#define OFF_HM2  20480
#define OFF_HM3  22528
#define OFF_HG   24576
#define OFF_HMG  25600
#define OFF_HM2G 26624

typedef __attribute__((ext_vector_type(8))) short bf16x8;
typedef __attribute__((ext_vector_type(4))) float f32x4;

__device__ __forceinline__ unsigned packhl(float v) {
  unsigned b = __float_as_uint(v);
  unsigned hi = (b + 0x7FFFu + ((b >> 16) & 1u)) & 0xFFFF0000u;
  float lo = v - __uint_as_float(hi);
  unsigned lb = __float_as_uint(lo);
  unsigned lo16 = ((lb + 0x7FFFu + ((lb >> 16) & 1u)) >> 16);
  return hi | (lo16 & 0xFFFFu);
}

__device__ __forceinline__ void frags_from(const unsigned* __restrict__ p,
                                           bf16x8& hi, bf16x8& lo) {
  uint4 a = *(const uint4*)p;
  uint4 b = *(const uint4*)(p + 4);
  unsigned u0=a.x,u1=a.y,u2=a.z,u3=a.w,u4=b.x,u5=b.y,u6=b.z,u7=b.w;
  hi[0]=(short)(u0>>16); hi[1]=(short)(u1>>16); hi[2]=(short)(u2>>16); hi[3]=(short)(u3>>16);
  hi[4]=(short)(u4>>16); hi[5]=(short)(u5>>16); hi[6]=(short)(u6>>16); hi[7]=(short)(u7>>16);
  lo[0]=(short)(u0&0xFFFFu); lo[1]=(short)(u1&0xFFFFu); lo[2]=(short)(u2&0xFFFFu); lo[3]=(short)(u3&0xFFFFu);
  lo[4]=(short)(u4&0xFFFFu); lo[5]=(short)(u5&0xFFFFu); lo[6]=(short)(u6&0xFFFFu); lo[7]=(short)(u7&0xFFFFu);
}

// c += A*B over 32 k (split-bf16: 3 mfma, lo*lo dropped)
__device__ __forceinline__ f32x4 mfma3(const unsigned* __restrict__ ap,
                                       const unsigned* __restrict__ bp, f32x4 c) {
  bf16x8 ah, al, bh, bl;
  frags_from(ap, ah, al);
  frags_from(bp, bh, bl);
  c = __builtin_amdgcn_mfma_f32_16x16x32_bf16(ah, bh, c, 0, 0, 0);
  c = __builtin_amdgcn_mfma_f32_16x16x32_bf16(ah, bl, c, 0, 0, 0);
  c = __builtin_amdgcn_mfma_f32_16x16x32_bf16(al, bh, c, 0, 0, 0);
  return c;
}

__device__ __forceinline__ float rdlane(float v, int lane) {
  return __uint_as_float(
      (unsigned)__builtin_amdgcn_readlane((int)__float_as_uint(v), lane));
}

__launch_bounds__(512)
__global__ void kf_phase1(const float* __restrict__ Fg,
                          const float* __restrict__ Hg,
                          const float* __restrict__ Rg,
                          const float* __restrict__ Qg,
                          float* __restrict__ ws) {
  __shared__ unsigned Fb [64*68];    // F packed; epilogue: M2
  __shared__ unsigned Pb [64*68];    // P packed (sym); epilogue: M
  __shared__ unsigned Wb [64*68];    // W = F*P packed; epilogue: M^T
  __shared__ unsigned M2tpb[64*68];  // epilogue only: (M^2)^T
  __shared__ unsigned Hb [32*68];    // H packed
  __shared__ unsigned Yb [32*68];    // Y = H*P packed; epilogue: G^T
  __shared__ unsigned Htb[64*36];    // H^T packed
  __shared__ unsigned Vb [64*36];    // V = W*H^T packed; epilogue: HM
  __shared__ unsigned Grb[64*36];    // -G packed
  __shared__ __align__(16) float Tf[64*65];     // T = W*F^T fp32
  __shared__ __align__(16) float Aug[32*100];   // [S | V^T] fp32
  __shared__ __align__(16) float prevG[64*33];  // fp32 G for convergence
  __shared__ int conv;

  const int tid = threadIdx.x;
  const int w = tid >> 6, lane = tid & 63, quad = lane >> 4, l16 = lane & 15;

  for (int s = tid; s < SD*SD; s += 512) {
    int i = s >> 6, j = s & 63;
    Fb[i*68 + j] = packhl(Fg[s]);
    Pb[i*68 + j] = packhl((i == j) ? 1.0f : 0.0f);
  }
  for (int s = tid; s < NV*SD; s += 512)
    Hb[(s>>6)*68 + (s&63)] = packhl(Hg[s]);
  for (int s = tid; s < SD*NV; s += 512) {
    int j = s >> 5, v = s & 31;
    Htb[j*36 + v] = packhl(Hg[v*SD + j]);
  }
  for (int s = tid; s < SD*NV; s += 512)
    prevG[(s>>5)*33 + (s&31)] = 1e30f;
  if (tid == 0) conv = 0;
  __syncthreads();

  int tcv = TMAX - 1;

  for (int t = 0; t < TMAX; ++t) {
    float* Mws = ws + (size_t)t * MG_STRIDE;
    float* Gws = Mws + SD*SD;

    // ---- A: Y = H*P (8 tiles) || W = F*P (16 tiles) ----
    for (int tt = w; tt < 24; tt += 8) {
      if (tt < 8) {
        const int m0 = (tt >> 2) << 4, n0 = (tt & 3) << 4;
        f32x4 c = {0.f, 0.f, 0.f, 0.f};
        c = mfma3(Hb + (m0+l16)*68 +      quad*8, Pb + (n0+l16)*68 +      quad*8, c);
        c = mfma3(Hb + (m0+l16)*68 + 32 + quad*8, Pb + (n0+l16)*68 + 32 + quad*8, c);
        const int r0 = m0 + quad*4, cc = n0 + l16;
        Yb[(r0+0)*68 + cc] = packhl(c[0]);
        Yb[(r0+1)*68 + cc] = packhl(c[1]);
        Yb[(r0+2)*68 + cc] = packhl(c[2]);
        Yb[(r0+3)*68 + cc] = packhl(c[3]);
      } else {
        const int ss = tt - 8;
        const int m0 = (ss >> 2) << 4, n0 = (ss & 3) << 4;
        f32x4 c = {0.f, 0.f, 0.f, 0.f};
        c = mfma3(Fb + (m0+l16)*68 +      quad*8, Pb + (n0+l16)*68 +      quad*8, c);
        c = mfma3(Fb + (m0+l16)*68 + 32 + quad*8, Pb + (n0+l16)*68 + 32 + quad*8, c);
        const int r0 = m0 + quad*4, cc = n0 + l16;
        Wb[(r0+0)*68 + cc] = packhl(c[0]);
        Wb[(r0+1)*68 + cc] = packhl(c[1]);
        Wb[(r0+2)*68 + cc] = packhl(c[2]);
        Wb[(r0+3)*68 + cc] = packhl(c[3]);
      }
    }
    __syncthreads();

    // ---- B: S = Y*H^T + R (4) || V = W*H^T (8) || T = W*F^T (16) ----
    for (int tt = w; tt < 28; tt += 8) {
      if (tt < 4) {
        const int m0 = (tt >> 1) << 4, n0 = (tt & 1) << 4;
        const int r0 = m0 + quad*4, cc = n0 + l16;
        f32x4 c;
        c[0] = Rg[(r0+0)*NV + cc];
        c[1] = Rg[(r0+1)*NV + cc];
        c[2] = Rg[(r0+2)*NV + cc];
        c[3] = Rg[(r0+3)*NV + cc];
        c = mfma3(Yb + (m0+l16)*68 +      quad*8, Hb + (n0+l16)*68 +      quad*8, c);
        c = mfma3(Yb + (m0+l16)*68 + 32 + quad*8, Hb + (n0+l16)*68 + 32 + quad*8, c);
        Aug[(r0+0)*100 + cc] = c[0];
        Aug[(r0+1)*100 + cc] = c[1];
        Aug[(r0+2)*100 + cc] = c[2];
        Aug[(r0+3)*100 + cc] = c[3];
      } else if (tt < 12) {
        const int ss = tt - 4;
        const int m0 = (ss >> 1) << 4, n0 = (ss & 1) << 4;
        f32x4 c = {0.f, 0.f, 0.f, 0.f};
        c = mfma3(Wb + (m0+l16)*68 +      quad*8, Hb + (n0+l16)*68 +      quad*8, c);
        c = mfma3(Wb + (m0+l16)*68 + 32 + quad*8, Hb + (n0+l16)*68 + 32 + quad*8, c);
        const int r0 = m0 + quad*4, cc = n0 + l16;
        Vb[(r0+0)*36 + cc] = packhl(c[0]);
        Vb[(r0+1)*36 + cc] = packhl(c[1]);
        Vb[(r0+2)*36 + cc] = packhl(c[2]);
        Vb[(r0+3)*36 + cc] = packhl(c[3]);
        *(float4*)(Aug + cc*100 + 32 + r0) = make_float4(c[0], c[1], c[2], c[3]);
      } else {
        const int ss = tt - 12;
        const int m0 = (ss >> 2) << 4, n0 = (ss & 3) << 4;
        f32x4 c = {0.f, 0.f, 0.f, 0.f};
        c = mfma3(Wb + (m0+l16)*68 +      quad*8, Fb + (n0+l16)*68 +      quad*8, c);
        c = mfma3(Wb + (m0+l16)*68 + 32 + quad*8, Fb + (n0+l16)*68 + 32 + quad*8, c);
        const int r0 = m0 + quad*4, cc = n0 + l16;
        Tf[(r0+0)*65 + cc] = c[0];
        Tf[(r0+1)*65 + cc] = c[1];
        Tf[(r0+2)*65 + cc] = c[2];
        Tf[(r0+3)*65 + cc] = c[3];
      }
    }
    __syncthreads();

    // ---- GJ on [S | V^T] in wave 0: G = V S^-1 (rows in lanes) ----
    if (tid < 64) {
      const int l = tid;
      float colA[32], colB[32];
      const int cbi = (l < 32) ? (64 + l) : 64;
#pragma unroll
      for (int r = 0; r < 32; ++r) {
        colA[r] = Aug[r*100 + l];
        colB[r] = Aug[r*100 + cbi];
      }
#pragma unroll
      for (int p = 0; p < 32; ++p) {
        const float piv = rdlane(colA[p], p);
        float inv = __builtin_amdgcn_rcpf(piv);
        inv = inv * (2.0f - piv * inv);          // 1 NR step
        const float rpA = colA[p] * inv;
        const float rpB = colB[p] * inv;
#pragma unroll
        for (int r = 0; r < 32; ++r) {
          if (r == p) continue;
          const float f = rdlane(colA[r], p);
          colA[r] -= f * rpA;
          colB[r] -= f * rpB;
        }
        colA[p] = rpA;
        colB[p] = rpB;
      }
      const int row = (l < 32) ? (32 + l) : (l - 32);
      float dmax = 0.0f;
#pragma unroll
      for (int r = 0; r < 32; ++r) {
        const float g = (l < 32) ? colB[r] : colA[r];
        Grb[row*36 + r] = packhl(-g);
        Gws[row*NV + r] = g;
        dmax = fmaxf(dmax, fabsf(g - prevG[row*33 + r]));
        prevG[row*33 + r] = g;
      }
#pragma unroll
      for (int off = 32; off >= 1; off >>= 1)
        dmax = fmaxf(dmax, __shfl_xor(dmax, off));
      if (l == 0) conv = (dmax < 1e-4f) ? 1 : 0;
    }
    __syncthreads();

    // ---- C: M = F - G*H -> ws (16) || P' = T - G*V^T + Q -> Pb (16) ----
    for (int tt = w; tt < 32; tt += 8) {
      if (tt < 16) {
        const int m0 = (tt >> 2) << 4, n0 = (tt & 3) << 4;
        const int r0 = m0 + quad*4, cc = n0 + l16;
        f32x4 c;
        c[0] = Fg[(r0+0)*SD + cc];
        c[1] = Fg[(r0+1)*SD + cc];
        c[2] = Fg[(r0+2)*SD + cc];
        c[3] = Fg[(r0+3)*SD + cc];
        c = mfma3(Grb + (m0+l16)*36 + quad*8, Htb + (n0+l16)*36 + quad*8, c);
        Mws[(r0+0)*SD + cc] = c[0];
        Mws[(r0+1)*SD + cc] = c[1];
        Mws[(r0+2)*SD + cc] = c[2];
        Mws[(r0+3)*SD + cc] = c[3];
      } else {
        const int ss = tt - 16;
        const int m0 = (ss >> 2) << 4, n0 = (ss & 3) << 4;
        const int r0 = m0 + quad*4, cc = n0 + l16;
        f32x4 c;
        c[0] = Tf[(r0+0)*65 + cc] + Qg[(r0+0)*SD + cc];
        c[1] = Tf[(r0+1)*65 + cc] + Qg[(r0+1)*SD + cc];
        c[2] = Tf[(r0+2)*65 + cc] + Qg[(r0+2)*SD + cc];
        c[3] = Tf[(r0+3)*65 + cc] + Qg[(r0+3)*SD + cc];
        c = mfma3(Grb + (m0+l16)*36 + quad*8, Vb + (n0+l16)*36 + quad*8, c);
        Pb[(r0+0)*68 + cc] = packhl(c[0]);
        Pb[(r0+1)*68 + cc] = packhl(c[1]);
        Pb[(r0+2)*68 + cc] = packhl(c[2]);
        Pb[(r0+3)*68 + cc] = packhl(c[3]);
      }
    }
    __syncthreads();

    if (conv) { tcv = t; break; }
  }
  if (tid == 0) ((int*)ws)[WS_TC] = tcv;

  // ---- epilogue: quad matrices of the converged system ----
  {
    const float* Mf = ws + (size_t)tcv * MG_STRIDE;
    const float* Gf = Mf + SD*SD;
    unsigned* Mp   = Pb;
    unsigned* Mtp  = Wb;
    unsigned* Gtp  = Yb;
    unsigned* M2p  = Fb;
    unsigned* M2tp = M2tpb;
    unsigned* MGtp = (unsigned*)Aug;   // 32x68 fits in 3200
    unsigned* HMp  = Vb;               // 32x68 fits in 64*36
    __syncthreads();
    for (int s = tid; s < SD*SD; s += 512) {
      int i = s >> 6, j = s & 63;
      unsigned pk = packhl(Mf[s]);
      Mp[i*68 + j] = pk;
      Mtp[j*68 + i] = pk;
    }
    for (int s = tid; s < SD*NV; s += 512) {
      int i = s >> 5, v = s & 31;
      Gtp[v*68 + i] = packhl(Gf[s]);
    }
    __syncthreads();

    float* M2o = ws + WS_PAIR;
    // E0: M2, M2^T, MG, HM, HG
    for (int tt = w; tt < 52; tt += 8) {
      if (tt < 16) {
        const int m0 = (tt >> 2) << 4, n0 = (tt & 3) << 4;
        f32x4 c = {0.f, 0.f, 0.f, 0.f};
        c = mfma3(Mp + (m0+l16)*68 +      quad*8, Mtp + (n0+l16)*68 +      quad*8, c);
        c = mfma3(Mp + (m0+l16)*68 + 32 + quad*8, Mtp + (n0+l16)*68 + 32 + quad*8, c);
        const int r0 = m0 + quad*4, cc = n0 + l16;
#pragma unroll
        for (int g = 0; g < 4; ++g) {
          M2o[OFF_M2 + (r0+g)*SD + cc] = c[g];
          M2p[(r0+g)*68 + cc] = packhl(c[g]);
        }
      } else if (tt < 32) {
        const int ss = tt - 16;
        const int m0 = (ss >> 2) << 4, n0 = (ss & 3) << 4;
        f32x4 c = {0.f, 0.f, 0.f, 0.f};
        c = mfma3(Mtp + (m0+l16)*68 +      quad*8, Mp + (n0+l16)*68 +      quad*8, c);
        c = mfma3(Mtp + (m0+l16)*68 + 32 + quad*8, Mp + (n0+l16)*68 + 32 + quad*8, c);
        const int r0 = m0 + quad*4, cc = n0 + l16;
#pragma unroll
        for (int g = 0; g < 4; ++g) M2tp[(r0+g)*68 + cc] = packhl(c[g]);
      } else if (tt < 40) {
        const int ss = tt - 32;
        const int m0 = (ss >> 1) << 4, n0 = (ss & 1) << 4;
        f32x4 c = {0.f, 0.f, 0.f, 0.f};
        c = mfma3(Mp + (m0+l16)*68 +      quad*8, Gtp + (n0+l16)*68 +      quad*8, c);
        c = mfma3(Mp + (m0+l16)*68 + 32 + quad*8, Gtp + (n0+l16)*68 + 32 + quad*8, c);
        const int r0 = m0 + quad*4, cc = n0 + l16;
#pragma unroll
        for (int g = 0; g < 4; ++g) M2o[OFF_MG + (r0+g)*NV + cc] = c[g];
        *(uint4*)(MGtp + cc*68 + r0) =
            make_uint4(packhl(c[0]), packhl(c[1]), packhl(c[2]), packhl(c[3]));
      } else if (tt < 48) {
        const int ss = tt - 40;
        const int m0 = (ss >> 2) << 4, n0 = (ss & 3) << 4;
        f32x4 c = {0.f, 0.f, 0.f, 0.f};
        c = mfma3(Hb + (m0+l16)*68 +      quad*8, Mtp + (n0+l16)*68 +      quad*8, c);
        c = mfma3(Hb + (m0+l16)*68 + 32 + quad*8, Mtp + (n0+l16)*68 + 32 + quad*8, c);
        const int r0 = m0 + quad*4, cc = n0 + l16;
#pragma unroll
        for (int g = 0; g < 4; ++g) {
          M2o[OFF_HM + (r0+g)*SD + cc] = c[g];
          HMp[(r0+g)*68 + cc] = packhl(c[g]);
        }
      } else {
        const int ss = tt - 48;
        const int m0 = (ss >> 1) << 4, n0 = (ss & 1) << 4;
        f32x4 c = {0.f, 0.f, 0.f, 0.f};
        c = mfma3(Hb + (m0+l16)*68 +      quad*8, Gtp + (n0+l16)*68 +      quad*8, c);
        c = mfma3(Hb + (m0+l16)*68 + 32 + quad*8, Gtp + (n0+l16)*68 + 32 + quad*8, c);
        const int r0 = m0 + quad*4, cc = n0 + l16;
#pragma unroll
        for (int g = 0; g < 4; ++g) M2o[OFF_HG + (r0+g)*NV + cc] = c[g];
      }
    }
    __syncthreads();

    // E1: M3, M4, M2G, M3G, HM2, HM3, HMG, HM2G
    for (int tt = w; tt < 72; tt += 8) {
      if (tt < 16) {
        const int m0 = (tt >> 2) << 4, n0 = (tt & 3) << 4;
        f32x4 c = {0.f, 0.f, 0.f, 0.f};
        c = mfma3(M2p + (m0+l16)*68 +      quad*8, Mtp + (n0+l16)*68 +      quad*8, c);
        c = mfma3(M2p + (m0+l16)*68 + 32 + quad*8, Mtp + (n0+l16)*68 + 32 + quad*8, c);
        const int r0 = m0 + quad*4, cc = n0 + l16;
#pragma unroll
        for (int g = 0; g < 4; ++g) M2o[OFF_M3 + (r0+g)*SD + cc] = c[g];
      } else if (tt < 32) {
        const int ss = tt - 16;
        const int m0 = (ss >> 2) << 4, n0 = (ss & 3) << 4;
        f32x4 c = {0.f, 0.f, 0.f, 0.f};
        c = mfma3(M2p + (m0+l16)*68 +      quad*8, M2tp + (n0+l16)*68 +      quad*8, c);
        c = mfma3(M2p + (m0+l16)*68 + 32 + quad*8, M2tp + (n0+l16)*68 + 32 + quad*8, c);
        const int r0 = m0 + quad*4, cc = n0 + l16;
#pragma unroll
        for (int g = 0; g < 4; ++g) M2o[OFF_M4 + (r0+g)*SD + cc] = c[g];
      } else if (tt < 40) {
        const int ss = tt - 32;
        const int m0 = (ss >> 1) << 4, n0 = (ss & 1) << 4;
        f32x4 c = {0.f, 0.f, 0.f, 0.f};
        c = mfma3(M2p + (m0+l16)*68 +      quad*8, Gtp + (n0+l16)*68 +      quad*8, c);
        c = mfma3(M2p + (m0+l16)*68 + 32 + quad*8, Gtp + (n0+l16)*68 + 32 + quad*8, c);
        const int r0 = m0 + quad*4, cc = n0 + l16;
#pragma unroll
        for (int g = 0; g < 4; ++g) M2o[OFF_M2G + (r0+g)*NV + cc] = c[g];
      } else if (tt < 48) {
        const int ss = tt - 40;
        const int m0 = (ss >> 1) << 4, n0 = (ss & 1) << 4;
        f32x4 c = {0.f, 0.f, 0.f, 0.f};
        c = mfma3(M2p + (m0+l16)*68 +      quad*8, MGtp + (n0+l16)*68 +      quad*8, c);
        c = mfma3(M2p + (m0+l16)*68 + 32 + quad*8, MGtp + (n0+l16)*68 + 32 + quad*8, c);
        const int r0 = m0 + quad*4, cc = n0 + l16;
#pragma unroll
        for (int g = 0; g < 4; ++g) M2o[OFF_M3G + (r0+g)*NV + cc] = c[g];
      } else if (tt < 56) {
        const int ss = tt - 48;
        const int m0 = (ss >> 2) << 4, n0 = (ss & 3) << 4;
        f32x4 c = {0.f, 0.f, 0.f, 0.f};
        c = mfma3(HMp + (m0+l16)*68 +      quad*8, Mtp + (n0+l16)*68 +      quad*8, c);
        c = mfma3(HMp + (m0+l16)*68 + 32 + quad*8, Mtp + (n0+l16)*68 + 32 + quad*8, c);
        const int r0 = m0 + quad*4, cc = n0 + l16;
#pragma unroll
        for (int g = 0; g < 4; ++g) M2o[OFF_HM2 + (r0+g)*SD + cc] = c[g];
      } else if (tt < 64) {
        const int ss = tt - 56;
        const int m0 = (ss >> 2) << 4, n0 = (ss & 3) << 4;
        f32x4 c = {0.f, 0.f, 0.f, 0.f};
        c = mfma3(HMp + (m0+l16)*68 +      quad*8, M2tp + (n0+l16)*68 +      quad*8, c);
        c = mfma3(HMp + (m0+l16)*68 + 32 + quad*8, M2tp + (n0+l16)*68 + 32 + quad*8, c);
        const int r0 = m0 + quad*4, cc = n0 + l16;
#pragma unroll
        for (int g = 0; g < 4; ++g) M2o[OFF_HM3 + (r0+g)*SD + cc] = c[g];
      } else if (tt < 68) {
        const int ss = tt - 64;
        const int m0 = (ss >> 1) << 4, n0 = (ss & 1) << 4;
        f32x4 c = {0.f, 0.f, 0.f, 0.f};
        c = mfma3(HMp + (m0+l16)*68 +      quad*8, Gtp + (n0+l16)*68 +      quad*8, c);
        c = mfma3(HMp + (m0+l16)*68 + 32 + quad*8, Gtp + (n0+l16)*68 + 32 + quad*8, c);
        const int r0 = m0 + quad*4, cc = n0 + l16;
#pragma unroll
        for (int g = 0; g < 4; ++g) M2o[OFF_HMG + (r0+g)*NV + cc] = c[g];
      } else {
        const int ss = tt - 68;
        const int m0 = (ss >> 1) << 4, n0 = (ss & 1) << 4;
        f32x4 c = {0.f, 0.f, 0.f, 0.f};
        c = mfma3(HMp + (m0+l16)*68 +      quad*8, MGtp + (n0+l16)*68 +      quad*8, c);
        c = mfma3(HMp + (m0+l16)*68 + 32 + quad*8, MGtp + (n0+l16)*68 + 32 + quad*8, c);
        const int r0 = m0 + quad*4, cc = n0 + l16;
#pragma unroll
        for (int g = 0; g < 4; ++g) M2o[OFF_HM2G + (r0+g)*NV + cc] = c[g];
      }
    }
  }
}

__launch_bounds__(256)
__global__ void kf_phase2(const float* __restrict__ x,
                          const float* __restrict__ Hg,
                          const float* __restrict__ ws,
                          float* __restrict__ out) {
  __shared__ __align__(16) float Hs2[NV*65];
  __shared__ __align__(16) float xt[132*36];
  __shared__ __align__(16) float yb[NV*129];
  __shared__ __align__(16) float mbuf[2*SD];
  __shared__ __align__(16) float M4s [SD*68];
  __shared__ __align__(16) float M3Gs[SD*36];
  __shared__ __align__(16) float M2Gs[SD*36];
  __shared__ __align__(16) float MGs [SD*36];
  __shared__ __align__(16) float Gs  [SD*36];
  __shared__ __align__(16) float HMs [NV*68];
  __shared__ __align__(16) float HM2s[NV*68];
  __shared__ __align__(16) float HM3s[NV*68];
  __shared__ __align__(16) float HGs [NV*36];
  __shared__ __align__(16) float HMGs[NV*36];
  __shared__ __align__(16) float HM2Gs[NV*36];
  const int tid = threadIdx.x, b = blockIdx.x;

  const int tc = ((const int*)ws)[WS_TC];
  const float* P = ws + WS_PAIR;
  const float* Gf = ws + (size_t)tc * MG_STRIDE + SD*SD;

  for (int s = tid; s < NV*SD; s += 256) {
    int v = s >> 6, j = s & 63;
    Hs2[v*65 + j] = Hg[s];
    HMs [v*68 + j] = P[OFF_HM  + s];
    HM2s[v*68 + j] = P[OFF_HM2 + s];
    HM3s[v*68 + j] = P[OFF_HM3 + s];
  }
  for (int s = tid; s < SD*SD; s += 256) M4s[(s>>6)*68 + (s&63)] = P[OFF_M4 + s];
  for (int s = tid; s < SD*NV; s += 256) {
    int i = s >> 5, v = s & 31;
    M3Gs[i*36 + v] = P[OFF_M3G + s];
    M2Gs[i*36 + v] = P[OFF_M2G + s];
    MGs [i*36 + v] = P[OFF_MG  + s];
    Gs  [i*36 + v] = Gf[s];
  }
  for (int s = tid; s < NV*NV; s += 256) {
    int v = s >> 5, u = s & 31;
    HGs  [v*36 + u] = P[OFF_HG   + s];
    HMGs [v*36 + u] = P[OFF_HMG  + s];
    HM2Gs[v*36 + u] = P[OFF_HM2G + s];
  }
  for (int s = tid; s < 4*36; s += 256) xt[128*36 + s] = 0.0f;
  for (int s = tid; s < NV*TSZ; s += 256) {
    int v = s >> 7, t = s & 127;
    xt[t*36 + v] = x[(size_t)b*NV*TSZ + s];
  }
  if (tid < NV) yb[tid*129] = 0.0f;
  if (tid < 2*SD) mbuf[tid] = 0.0f;
  __syncthreads();

  const int i = tid >> 2, p4 = tid & 3;
  const int v = tid >> 3, p8 = tid & 7;
  int cb = 0;

  for (int t = 0; t < tc; ++t) {
    const float* Mt = ws + (size_t)t * MG_STRIDE;
    const float* Gt = Mt + SD*SD;
    const float* cur = mbuf + cb * SD;
    float*       nxt = mbuf + (cb ^ 1) * SD;

    float acc = 0.0f;
    {
      const int j0 = p4 * 16;
#pragma unroll
      for (int c = 0; c < 16; c += 4) {
        float4 mm = *(const float4*)(Mt + i*SD + j0 + c);
        float4 vv = *(const float4*)(cur + j0 + c);
        acc += mm.x*vv.x + mm.y*vv.y + mm.z*vv.z + mm.w*vv.w;
      }
      const int v0 = p4 * 8;
#pragma unroll
      for (int c = 0; c < 8; c += 4) {
        float4 gg = *(const float4*)(Gt + i*NV + v0 + c);
        float4 oo = *(const float4*)(xt + t*36 + v0 + c);
        acc += gg.x*oo.x + gg.y*oo.y + gg.z*oo.z + gg.w*oo.w;
      }
    }
    acc += __shfl_xor(acc, 1);
    acc += __shfl_xor(acc, 2);

    if (t >= 1) {
      float ys = 0.0f;
#pragma unroll
      for (int j = 0; j < 8; ++j)
        ys += Hs2[v*65 + p8*8 + j] * cur[p8*8 + j];
      ys += __shfl_xor(ys, 1);
      ys += __shfl_xor(ys, 2);
      ys += __shfl_xor(ys, 4);
      if (p8 == 0) yb[v*129 + t] = ys;
    }
    if (p4 == 0) nxt[i] = acc;
    __syncthreads();
    cb ^= 1;
  }

  for (int t = tc; t < TSZ; t += 4) {
    const float* cur = mbuf + cb * SD;
    float*       nxt = mbuf + (cb ^ 1) * SD;
    const float* o0 = xt + t*36;
    const float* o1 = o0 + 36;
    const float* o2 = o1 + 36;
    const float* o3 = o2 + 36;

    {
      const int j8 = p8 * 8, j4 = p8 * 4;
      float y0 = 0.f, y1 = 0.f, y2 = 0.f, y3 = 0.f;
#pragma unroll
      for (int c = 0; c < 8; c += 4) {
        float4 vv = *(const float4*)(cur + j8 + c);
        float4 h0 = *(const float4*)(Hs2 + v*65 + j8 + c);
        float4 h1 = *(const float4*)(HMs + v*68 + j8 + c);
        float4 h2 = *(const float4*)(HM2s + v*68 + j8 + c);
        float4 h3 = *(const float4*)(HM3s + v*68 + j8 + c);
        y0 += h0.x*vv.x + h0.y*vv.y + h0.z*vv.z + h0.w*vv.w;
        y1 += h1.x*vv.x + h1.y*vv.y + h1.z*vv.z + h1.w*vv.w;
        y2 += h2.x*vv.x + h2.y*vv.y + h2.z*vv.z + h2.w*vv.w;
        y3 += h3.x*vv.x + h3.y*vv.y + h3.z*vv.z + h3.w*vv.w;
      }
      {
        float4 a = *(const float4*)(HGs + v*36 + j4);
        float4 bq = *(const float4*)(HMGs + v*36 + j4);
        float4 cq = *(const float4*)(HM2Gs + v*36 + j4);
        float4 q0 = *(const float4*)(o0 + j4);
        float4 q1 = *(const float4*)(o1 + j4);
        float4 q2 = *(const float4*)(o2 + j4);
        y1 += a.x*q0.x + a.y*q0.y + a.z*q0.z + a.w*q0.w;
        y2 += bq.x*q0.x + bq.y*q0.y + bq.z*q0.z + bq.w*q0.w
            + a.x*q1.x + a.y*q1.y + a.z*q1.z + a.w*q1.w;
        y3 += cq.x*q0.x + cq.y*q0.y + cq.z*q0.z + cq.w*q0.w
            + bq.x*q1.x + bq.y*q1.y + bq.z*q1.z + bq.w*q1.w
            + a.x*q2.x + a.y*q2.y + a.z*q2.z + a.w*q2.w;
      }
#pragma unroll
      for (int off = 1; off <= 4; off <<= 1) {
        y0 += __shfl_xor(y0, off);
        y1 += __shfl_xor(y1, off);
        y2 += __shfl_xor(y2, off);
        y3 += __shfl_xor(y3, off);
      }
      if (p8 == 0) {
        yb[v*129 + t] = y0;
        if (t + 1 < TSZ) yb[v*129 + t + 1] = y1;
        if (t + 2 < TSZ) yb[v*129 + t + 2] = y2;
        if (t + 3 < TSZ) yb[v*129 + t + 3] = y3;
      }
    }

    {
      float acc = 0.0f;
      const int j0 = p4 * 16;
#pragma unroll
      for (int c = 0; c < 16; c += 4) {
        float4 mm = *(const float4*)(M4s + i*68 + j0 + c);
        float4 vv = *(const float4*)(cur + j0 + c);
        acc += mm.x*vv.x + mm.y*vv.y + mm.z*vv.z + mm.w*vv.w;
      }
      const int v0 = p4 * 8;
#pragma unroll
      for (int c = 0; c < 8; c += 4) {
        float4 g3 = *(const float4*)(M3Gs + i*36 + v0 + c);
        float4 g2 = *(const float4*)(M2Gs + i*36 + v0 + c);
        float4 g1 = *(const float4*)(MGs + i*36 + v0 + c);
        float4 g0 = *(const float4*)(Gs + i*36 + v0 + c);
        float4 q0 = *(const float4*)(o0 + v0 + c);
        float4 q1 = *(const float4*)(o1 + v0 + c);
        float4 q2 = *(const float4*)(o2 + v0 + c);
        float4 q3 = *(const float4*)(o3 + v0 + c);
        acc += g3.x*q0.x + g3.y*q0.y + g3.z*q0.z + g3.w*q0.w;
        acc += g2.x*q1.x + g2.y*q1.y + g2.z*q1.z + g2.w*q1.w;
        acc += g1.x*q2.x + g1.y*q2.y + g1.z*q2.z + g1.w*q2.w;
        acc += g0.x*q3.x + g0.y*q3.y + g0.z*q3.z + g0.w*q3.w;
      }
      acc += __shfl_xor(acc, 1);
      acc += __shfl_xor(acc, 2);
      if (p4 == 0) nxt[i] = acc;
    }
    __syncthreads();
    cb ^= 1;
  }

  for (int s = tid; s < NV*TSZ; s += 256)
    out[(size_t)b*NV*TSZ + s] = yb[(s>>7)*129 + (s&127)];
}

extern "C" void kernel_launch(void* const* d_in, const int* in_sizes, int n_in,
                              void* d_out, int out_size, void* d_ws, size_t ws_size,
                              hipStream_t stream) {
  const float* x = (const float*)d_in[0];
  const float* F = (const float*)d_in[1];
  const float* H = (const float*)d_in[2];
  const float* R = (const float*)d_in[3];
  const float* Q = (const float*)d_in[4];
  float* out = (float*)d_out;
  float* ws  = (float*)d_ws;   // ~3.06 MB used

  hipLaunchKernelGGL(kf_phase1, dim3(1), dim3(512), 0, stream, F, H, R, Q, ws);
  hipLaunchKernelGGL(kf_phase2, dim3(BSZ), dim3(256), 0, stream, x, H, ws, out);
}

// Round 7
// 199.338 us; speedup vs baseline: 1.7449x; 1.2019x over previous
//
#include <hip/hip_runtime.h>

// Kalman filter forward. out[b,v,t] (t>=1) = H m_t,
//   m_{t+1} = M_t m_t + G_t x[:,:,t],  M_t = F(I-K_t H), G_t = F K_t.
// K_t is batch-independent (P0 = I).
// R7 theory: R3-R6 show per-step time ~constant (~23us) regardless of barrier
// count => step-loop body (~37KB, unrolled GJ) thrashes the 32KB L1 I-cache
// every iteration. Fix: shrink code. GJ inverts [S|I] only (64 lanes x 32
// regs, ~2.2K instrs); G = V*Sinv via MFMA (Sinv symmetric => row-major is
// the B^T layout). Epilogue = descriptor-driven generic tile executor.
// Phases/step: A(Y,W) B(S,V) GJ||T D(G,conv) C(M,P').
// Phase 2 (128 blocks): transient single steps then quad steps (unchanged).

#define SD 64
#define NV 32
#define TSZ 128
#define BSZ 128
#define TMAX 120

#define MG_STRIDE (SD*SD + SD*NV)           // 6144 floats per step: M then G
#define WS_PAIR (120*MG_STRIDE)             // quad-matrix block (27648 floats)
#define WS_TC   (WS_PAIR + 27648)           // int: converged step index
#define OFF_M2   0
#define OFF_M3   4096
#define OFF_M4   8192
#define OFF_MG   12288
#define OFF_M2G  14336
#define OFF_M3G  16384
#define OFF_HM   18432
#define OFF_HM2  20480
#define OFF_HM3  22528
#define OFF_HG   24576
#define OFF_HMG  25600
#define OFF_HM2G 26624

// ---- phase-1 LDS arena offsets (u32 words) ----
#define AFB    0        // F packed ld68 (4352); epilogue: M2 packed
#define APB    4352     // P packed ld68 (4352); epilogue: M packed
#define AWB    8704     // W=F*P packed ld68 (4352); epilogue: M^T packed
#define AHB    13056    // H packed ld68 (2176)
#define AHTB   15232    // H^T packed ld36 (2304)   \ contiguous: epilogue
#define AGRB   17536    // -G packed ld36 (2304)    / (M^2)^T ld68 (4352)
#define AVB    19840    // V packed ld36 (2304); epilogue: HM packed ld68
#define AYB    22144    // Y=H*P packed ld68 (2176); epilogue: G^T packed ld68
#define ASIP   24320    // Sinv packed ld36 (1152)
#define ATF    25472    // T fp32 ld65 (4160); epilogue: (MG)^T packed ld68
#define ASF    29632    // S fp32 ld33 (1056)
#define APREVG 30688    // prev G fp32 ld33 (2112)
#define AWRED  32800    // fp32 x8
#define ASZ    32808    // 131232 B

typedef __attribute__((ext_vector_type(8))) short bf16x8;
typedef __attribute__((ext_vector_type(4))) float f32x4;

__device__ __forceinline__ unsigned packhl(float v) {
  unsigned b = __float_as_uint(v);
  unsigned hi = (b + 0x7FFFu + ((b >> 16) & 1u)) & 0xFFFF0000u;
  float lo = v - __uint_as_float(hi);
  unsigned lb = __float_as_uint(lo);
  unsigned lo16 = ((lb + 0x7FFFu + ((lb >> 16) & 1u)) >> 16);
  return hi | (lo16 & 0xFFFFu);
}

__device__ __forceinline__ void frags_from(const unsigned* __restrict__ p,
                                           bf16x8& hi, bf16x8& lo) {
  uint4 a = *(const uint4*)p;
  uint4 b = *(const uint4*)(p + 4);
  unsigned u0=a.x,u1=a.y,u2=a.z,u3=a.w,u4=b.x,u5=b.y,u6=b.z,u7=b.w;
  hi[0]=(short)(u0>>16); hi[1]=(short)(u1>>16); hi[2]=(short)(u2>>16); hi[3]=(short)(u3>>16);
  hi[4]=(short)(u4>>16); hi[5]=(short)(u5>>16); hi[6]=(short)(u6>>16); hi[7]=(short)(u7>>16);
  lo[0]=(short)(u0&0xFFFFu); lo[1]=(short)(u1&0xFFFFu); lo[2]=(short)(u2&0xFFFFu); lo[3]=(short)(u3&0xFFFFu);
  lo[4]=(short)(u4&0xFFFFu); lo[5]=(short)(u5&0xFFFFu); lo[6]=(short)(u6&0xFFFFu); lo[7]=(short)(u7&0xFFFFu);
}

// c += A*B over 32 k (split-bf16: 3 mfma, lo*lo dropped)
__device__ __forceinline__ f32x4 mfma3(const unsigned* __restrict__ ap,
                                       const unsigned* __restrict__ bp, f32x4 c) {
  bf16x8 ah, al, bh, bl;
  frags_from(ap, ah, al);
  frags_from(bp, bh, bl);
  c = __builtin_amdgcn_mfma_f32_16x16x32_bf16(ah, bh, c, 0, 0, 0);
  c = __builtin_amdgcn_mfma_f32_16x16x32_bf16(ah, bl, c, 0, 0, 0);
  c = __builtin_amdgcn_mfma_f32_16x16x32_bf16(al, bh, c, 0, 0, 0);
  return c;
}

__device__ __forceinline__ float rdlane(float v, int lane) {
  return __uint_as_float(
      (unsigned)__builtin_amdgcn_readlane((int)__float_as_uint(v), lane));
}

// epilogue product descriptors: {aOff, bOff, wsOut(-1 none), outLd, nTshift,
//                                tiles, packOff(-1 none), packMode(1 row, 2 T)}
__device__ const int DE0[5][8] = {
  {APB, AWB, OFF_M2, 64, 2, 16, AFB,  1},   // M2 = M*M      (+packed)
  {AWB, APB, -1,     64, 2, 16, AHTB, 1},   // (M2)^T = MT*MT (packed only)
  {APB, AYB, OFF_MG, 32, 1, 8,  ATF,  2},   // MG = M*G      (+packed^T)
  {AHB, AWB, OFF_HM, 64, 2, 8,  AVB,  1},   // HM = H*M      (+packed)
  {AHB, AYB, OFF_HG, 32, 1, 4,  -1,   0},   // HG = H*G
};
__device__ const int DE1[8][8] = {
  {AFB, AWB,  OFF_M3,   64, 2, 16, -1, 0},  // M3 = M2*M
  {AFB, AHTB, OFF_M4,   64, 2, 16, -1, 0},  // M4 = M2*M2
  {AFB, AYB,  OFF_M2G,  32, 1, 8,  -1, 0},  // M2G = M2*G
  {AFB, ATF,  OFF_M3G,  32, 1, 8,  -1, 0},  // M3G = M2*MG
  {AVB, AWB,  OFF_HM2,  64, 2, 8,  -1, 0},  // HM2 = HM*M
  {AVB, AHTB, OFF_HM3,  64, 2, 8,  -1, 0},  // HM3 = HM*M2
  {AVB, AYB,  OFF_HMG,  32, 1, 4,  -1, 0},  // HMG = HM*G
  {AVB, ATF,  OFF_HM2G, 32, 1, 4,  -1, 0},  // HM2G = HM*MG
};

__device__ __forceinline__ void run_desc(const int (*D)[8], int nD, int totT,
                                         unsigned* U, float* M2o,
                                         int w, int l16, int quad) {
  for (int gt = w; gt < totT; gt += 8) {
    int ti = gt, di = 0;
    while (ti >= D[di][5]) { ti -= D[di][5]; ++di; }
    const int* d = D[di];
    const int nTs = d[4];
    const int m0 = (ti >> nTs) << 4, n0 = (ti & ((1 << nTs) - 1)) << 4;
    f32x4 c = {0.f, 0.f, 0.f, 0.f};
    const unsigned* ap = U + d[0] + (m0 + l16) * 68 + quad * 8;
    const unsigned* bp = U + d[1] + (n0 + l16) * 68 + quad * 8;
    c = mfma3(ap, bp, c);
    c = mfma3(ap + 32, bp + 32, c);
    const int r0 = m0 + quad * 4, cc = n0 + l16;
    if (d[2] >= 0) {
#pragma unroll
      for (int g = 0; g < 4; ++g) M2o[d[2] + (r0 + g) * d[3] + cc] = c[g];
    }
    if (d[7] == 1) {
#pragma unroll
      for (int g = 0; g < 4; ++g) U[d[6] + (r0 + g) * 68 + cc] = packhl(c[g]);
    } else if (d[7] == 2) {
      *(uint4*)(U + d[6] + cc * 68 + r0) =
          make_uint4(packhl(c[0]), packhl(c[1]), packhl(c[2]), packhl(c[3]));
    }
  }
}

__launch_bounds__(512)
__global__ void kf_phase1(const float* __restrict__ Fg,
                          const float* __restrict__ Hg,
                          const float* __restrict__ Rg,
                          const float* __restrict__ Qg,
                          float* __restrict__ ws) {
  __shared__ unsigned AR[ASZ];
  unsigned* U = AR;
  float* Ff = (float*)AR;

  const int tid = threadIdx.x;
  const int w = tid >> 6, lane = tid & 63, quad = lane >> 4, l16 = lane & 15;

  // ---- prep: pack F, H, H^T; P = I; prevG = big ----
  for (int s = tid; s < SD*SD; s += 512) {
    int i = s >> 6, j = s & 63;
    U[AFB + i*68 + j] = packhl(Fg[s]);
    U[APB + i*68 + j] = packhl((i == j) ? 1.0f : 0.0f);
  }
  for (int s = tid; s < NV*SD; s += 512)
    U[AHB + (s>>6)*68 + (s&63)] = packhl(Hg[s]);
  for (int s = tid; s < SD*NV; s += 512) {
    int j = s >> 5, v = s & 31;
    U[AHTB + j*36 + v] = packhl(Hg[v*SD + j]);
    Ff[APREVG + j*33 + v] = 1e30f;
  }
  __syncthreads();

  int tcv = TMAX - 1;

  for (int t = 0; t < TMAX; ++t) {
    float* Mws = ws + (size_t)t * MG_STRIDE;
    float* Gws = Mws + SD*SD;

    // ---- A: Y = H*P (8 tiles) || W = F*P (16 tiles) ----
    for (int tt = w; tt < 24; tt += 8) {
      if (tt < 8) {
        const int m0 = (tt >> 2) << 4, n0 = (tt & 3) << 4;
        f32x4 c = {0.f, 0.f, 0.f, 0.f};
        c = mfma3(U + AHB + (m0+l16)*68 +      quad*8, U + APB + (n0+l16)*68 +      quad*8, c);
        c = mfma3(U + AHB + (m0+l16)*68 + 32 + quad*8, U + APB + (n0+l16)*68 + 32 + quad*8, c);
        const int r0 = m0 + quad*4, cc = n0 + l16;
        U[AYB + (r0+0)*68 + cc] = packhl(c[0]);
        U[AYB + (r0+1)*68 + cc] = packhl(c[1]);
        U[AYB + (r0+2)*68 + cc] = packhl(c[2]);
        U[AYB + (r0+3)*68 + cc] = packhl(c[3]);
      } else {
        const int ss = tt - 8;
        const int m0 = (ss >> 2) << 4, n0 = (ss & 3) << 4;
        f32x4 c = {0.f, 0.f, 0.f, 0.f};
        c = mfma3(U + AFB + (m0+l16)*68 +      quad*8, U + APB + (n0+l16)*68 +      quad*8, c);
        c = mfma3(U + AFB + (m0+l16)*68 + 32 + quad*8, U + APB + (n0+l16)*68 + 32 + quad*8, c);
        const int r0 = m0 + quad*4, cc = n0 + l16;
        U[AWB + (r0+0)*68 + cc] = packhl(c[0]);
        U[AWB + (r0+1)*68 + cc] = packhl(c[1]);
        U[AWB + (r0+2)*68 + cc] = packhl(c[2]);
        U[AWB + (r0+3)*68 + cc] = packhl(c[3]);
      }
    }
    __syncthreads();

    // ---- B: S = Y*H^T + R -> Sf (4 tiles) || V = W*H^T -> Vb (8 tiles) ----
    for (int tt = w; tt < 12; tt += 8) {
      if (tt < 4) {
        const int m0 = (tt >> 1) << 4, n0 = (tt & 1) << 4;
        const int r0 = m0 + quad*4, cc = n0 + l16;
        f32x4 c;
        c[0] = Rg[(r0+0)*NV + cc];
        c[1] = Rg[(r0+1)*NV + cc];
        c[2] = Rg[(r0+2)*NV + cc];
        c[3] = Rg[(r0+3)*NV + cc];
        c = mfma3(U + AYB + (m0+l16)*68 +      quad*8, U + AHB + (n0+l16)*68 +      quad*8, c);
        c = mfma3(U + AYB + (m0+l16)*68 + 32 + quad*8, U + AHB + (n0+l16)*68 + 32 + quad*8, c);
        Ff[ASF + (r0+0)*33 + cc] = c[0];
        Ff[ASF + (r0+1)*33 + cc] = c[1];
        Ff[ASF + (r0+2)*33 + cc] = c[2];
        Ff[ASF + (r0+3)*33 + cc] = c[3];
      } else {
        const int ss = tt - 4;
        const int m0 = (ss >> 1) << 4, n0 = (ss & 1) << 4;
        f32x4 c = {0.f, 0.f, 0.f, 0.f};
        c = mfma3(U + AWB + (m0+l16)*68 +      quad*8, U + AHB + (n0+l16)*68 +      quad*8, c);
        c = mfma3(U + AWB + (m0+l16)*68 + 32 + quad*8, U + AHB + (n0+l16)*68 + 32 + quad*8, c);
        const int r0 = m0 + quad*4, cc = n0 + l16;
        U[AVB + (r0+0)*36 + cc] = packhl(c[0]);
        U[AVB + (r0+1)*36 + cc] = packhl(c[1]);
        U[AVB + (r0+2)*36 + cc] = packhl(c[2]);
        U[AVB + (r0+3)*36 + cc] = packhl(c[3]);
      }
    }
    __syncthreads();

    // ---- GJ on [S|I] in wave 0 (no barriers) || T = W*F^T (waves 1-7) ----
    if (tid < 64) {
      const int l = tid;
      float colX[32];
      if (l < 32) {
#pragma unroll
        for (int r = 0; r < 32; ++r) colX[r] = Ff[ASF + r*33 + l];
      } else {
#pragma unroll
        for (int r = 0; r < 32; ++r) colX[r] = (r == l - 32) ? 1.0f : 0.0f;
      }
#pragma unroll
      for (int p = 0; p < 32; ++p) {
        const float piv = rdlane(colX[p], p);
        float inv = __builtin_amdgcn_rcpf(piv);
        inv = inv * (2.0f - piv * inv);          // 1 NR step
        const float rp = colX[p] * inv;
#pragma unroll
        for (int r = 0; r < 32; ++r) {
          if (r == p) continue;
          const float f = rdlane(colX[r], p);
          colX[r] -= f * rp;
        }
        colX[p] = rp;
      }
      if (l >= 32) {
        const int c = l - 32;                    // Sinv col c (== row c, sym)
#pragma unroll
        for (int r = 0; r < 32; ++r)
          U[ASIP + r*36 + c] = packhl(colX[r]);
      }
    } else {
      for (int tt = w - 1; tt < 16; tt += 7) {
        const int m0 = (tt >> 2) << 4, n0 = (tt & 3) << 4;
        f32x4 c = {0.f, 0.f, 0.f, 0.f};
        c = mfma3(U + AWB + (m0+l16)*68 +      quad*8, U + AFB + (n0+l16)*68 +      quad*8, c);
        c = mfma3(U + AWB + (m0+l16)*68 + 32 + quad*8, U + AFB + (n0+l16)*68 + 32 + quad*8, c);
        const int r0 = m0 + quad*4, cc = n0 + l16;
        Ff[ATF + (r0+0)*65 + cc] = c[0];
        Ff[ATF + (r0+1)*65 + cc] = c[1];
        Ff[ATF + (r0+2)*65 + cc] = c[2];
        Ff[ATF + (r0+3)*65 + cc] = c[3];
      }
    }
    __syncthreads();

    // ---- D: G = V * Sinv (8 tiles, one per wave) + convergence ----
    {
      const int m0 = (w >> 1) << 4, n0 = (w & 1) << 4;
      f32x4 c = {0.f, 0.f, 0.f, 0.f};
      c = mfma3(U + AVB + (m0+l16)*36 + quad*8, U + ASIP + (n0+l16)*36 + quad*8, c);
      const int r0 = m0 + quad*4, cc = n0 + l16;
      float dmax = 0.0f;
#pragma unroll
      for (int g = 0; g < 4; ++g) {
        const float gv = c[g];
        Gws[(r0+g)*NV + cc] = gv;
        U[AGRB + (r0+g)*36 + cc] = packhl(-gv);
        dmax = fmaxf(dmax, fabsf(gv - Ff[APREVG + (r0+g)*33 + cc]));
        Ff[APREVG + (r0+g)*33 + cc] = gv;
      }
#pragma unroll
      for (int off = 32; off >= 1; off >>= 1)
        dmax = fmaxf(dmax, __shfl_xor(dmax, off));
      if (lane == 0) Ff[AWRED + w] = dmax;
    }
    __syncthreads();

    // ---- C: M = F - G*H -> ws (16) || P' = T - G*V^T + Q -> Pb (16) ----
    for (int tt = w; tt < 32; tt += 8) {
      if (tt < 16) {
        const int m0 = (tt >> 2) << 4, n0 = (tt & 3) << 4;
        const int r0 = m0 + quad*4, cc = n0 + l16;
        f32x4 c;
        c[0] = Fg[(r0+0)*SD + cc];
        c[1] = Fg[(r0+1)*SD + cc];
        c[2] = Fg[(r0+2)*SD + cc];
        c[3] = Fg[(r0+3)*SD + cc];
        c = mfma3(U + AGRB + (m0+l16)*36 + quad*8, U + AHTB + (n0+l16)*36 + quad*8, c);
        Mws[(r0+0)*SD + cc] = c[0];
        Mws[(r0+1)*SD + cc] = c[1];
        Mws[(r0+2)*SD + cc] = c[2];
        Mws[(r0+3)*SD + cc] = c[3];
      } else {
        const int ss = tt - 16;
        const int m0 = (ss >> 2) << 4, n0 = (ss & 3) << 4;
        const int r0 = m0 + quad*4, cc = n0 + l16;
        f32x4 c;
        c[0] = Ff[ATF + (r0+0)*65 + cc] + Qg[(r0+0)*SD + cc];
        c[1] = Ff[ATF + (r0+1)*65 + cc] + Qg[(r0+1)*SD + cc];
        c[2] = Ff[ATF + (r0+2)*65 + cc] + Qg[(r0+2)*SD + cc];
        c[3] = Ff[ATF + (r0+3)*65 + cc] + Qg[(r0+3)*SD + cc];
        c = mfma3(U + AGRB + (m0+l16)*36 + quad*8, U + AVB + (n0+l16)*36 + quad*8, c);
        U[APB + (r0+0)*68 + cc] = packhl(c[0]);
        U[APB + (r0+1)*68 + cc] = packhl(c[1]);
        U[APB + (r0+2)*68 + cc] = packhl(c[2]);
        U[APB + (r0+3)*68 + cc] = packhl(c[3]);
      }
    }
    __syncthreads();

    float cm = Ff[AWRED + 0];
#pragma unroll
    for (int k = 1; k < 8; ++k) cm = fmaxf(cm, Ff[AWRED + k]);
    if (cm < 3e-4f) { tcv = t; break; }
  }
  if (tid == 0) ((int*)ws)[WS_TC] = tcv;

  // ---- epilogue: quad matrices via descriptor executor ----
  {
    const float* Mf = ws + (size_t)tcv * MG_STRIDE;
    const float* Gf = Mf + SD*SD;
    for (int s = tid; s < SD*SD; s += 512) {
      int i = s >> 6, j = s & 63;
      unsigned pk = packhl(Mf[s]);
      U[APB + i*68 + j] = pk;        // M
      U[AWB + j*68 + i] = pk;        // M^T
    }
    for (int s = tid; s < SD*NV; s += 512) {
      int i = s >> 5, v = s & 31;
      U[AYB + v*68 + i] = packhl(Gf[s]);   // G^T
    }
    __syncthreads();
    float* M2o = ws + WS_PAIR;
    run_desc(DE0, 5, 52, U, M2o, w, l16, quad);
    __syncthreads();
    run_desc(DE1, 8, 72, U, M2o, w, l16, quad);
  }
}

__launch_bounds__(256)
__global__ void kf_phase2(const float* __restrict__ x,
                          const float* __restrict__ Hg,
                          const float* __restrict__ ws,
                          float* __restrict__ out) {
  __shared__ __align__(16) float Hs2[NV*65];
  __shared__ __align__(16) float xt[132*36];
  __shared__ __align__(16) float yb[NV*129];
  __shared__ __align__(16) float mbuf[2*SD];
  __shared__ __align__(16) float M4s [SD*68];
  __shared__ __align__(16) float M3Gs[SD*36];
  __shared__ __align__(16) float M2Gs[SD*36];
  __shared__ __align__(16) float MGs [SD*36];
  __shared__ __align__(16) float Gs  [SD*36];
  __shared__ __align__(16) float HMs [NV*68];
  __shared__ __align__(16) float HM2s[NV*68];
  __shared__ __align__(16) float HM3s[NV*68];
  __shared__ __align__(16) float HGs [NV*36];
  __shared__ __align__(16) float HMGs[NV*36];
  __shared__ __align__(16) float HM2Gs[NV*36];
  const int tid = threadIdx.x, b = blockIdx.x;

  const int tc = ((const int*)ws)[WS_TC];
  const float* P = ws + WS_PAIR;
  const float* Gf = ws + (size_t)tc * MG_STRIDE + SD*SD;

  for (int s = tid; s < NV*SD; s += 256) {
    int v = s >> 6, j = s & 63;
    Hs2[v*65 + j] = Hg[s];
    HMs [v*68 + j] = P[OFF_HM  + s];
    HM2s[v*68 + j] = P[OFF_HM2 + s];
    HM3s[v*68 + j] = P[OFF_HM3 + s];
  }
  for (int s = tid; s < SD*SD; s += 256) M4s[(s>>6)*68 + (s&63)] = P[OFF_M4 + s];
  for (int s = tid; s < SD*NV; s += 256) {
    int i = s >> 5, v = s & 31;
    M3Gs[i*36 + v] = P[OFF_M3G + s];
    M2Gs[i*36 + v] = P[OFF_M2G + s];
    MGs [i*36 + v] = P[OFF_MG  + s];
    Gs  [i*36 + v] = Gf[s];
  }
  for (int s = tid; s < NV*NV; s += 256) {
    int v = s >> 5, u = s & 31;
    HGs  [v*36 + u] = P[OFF_HG   + s];
    HMGs [v*36 + u] = P[OFF_HMG  + s];
    HM2Gs[v*36 + u] = P[OFF_HM2G + s];
  }
  for (int s = tid; s < 4*36; s += 256) xt[128*36 + s] = 0.0f;
  for (int s = tid; s < NV*TSZ; s += 256) {
    int v = s >> 7, t = s & 127;
    xt[t*36 + v] = x[(size_t)b*NV*TSZ + s];
  }
  if (tid < NV) yb[tid*129] = 0.0f;
  if (tid < 2*SD) mbuf[tid] = 0.0f;
  __syncthreads();

  const int i = tid >> 2, p4 = tid & 3;
  const int v = tid >> 3, p8 = tid & 7;
  int cb = 0;

  for (int t = 0; t < tc; ++t) {
    const float* Mt = ws + (size_t)t * MG_STRIDE;
    const float* Gt = Mt + SD*SD;
    const float* cur = mbuf + cb * SD;
    float*       nxt = mbuf + (cb ^ 1) * SD;

    float acc = 0.0f;
    {
      const int j0 = p4 * 16;
#pragma unroll
      for (int c = 0; c < 16; c += 4) {
        float4 mm = *(const float4*)(Mt + i*SD + j0 + c);
        float4 vv = *(const float4*)(cur + j0 + c);
        acc += mm.x*vv.x + mm.y*vv.y + mm.z*vv.z + mm.w*vv.w;
      }
      const int v0 = p4 * 8;
#pragma unroll
      for (int c = 0; c < 8; c += 4) {
        float4 gg = *(const float4*)(Gt + i*NV + v0 + c);
        float4 oo = *(const float4*)(xt + t*36 + v0 + c);
        acc += gg.x*oo.x + gg.y*oo.y + gg.z*oo.z + gg.w*oo.w;
      }
    }
    acc += __shfl_xor(acc, 1);
    acc += __shfl_xor(acc, 2);

    if (t >= 1) {
      float ys = 0.0f;
#pragma unroll
      for (int j = 0; j < 8; ++j)
        ys += Hs2[v*65 + p8*8 + j] * cur[p8*8 + j];
      ys += __shfl_xor(ys, 1);
      ys += __shfl_xor(ys, 2);
      ys += __shfl_xor(ys, 4);
      if (p8 == 0) yb[v*129 + t] = ys;
    }
    if (p4 == 0) nxt[i] = acc;
    __syncthreads();
    cb ^= 1;
  }

  for (int t = tc; t < TSZ; t += 4) {
    const float* cur = mbuf + cb * SD;
    float*       nxt = mbuf + (cb ^ 1) * SD;
    const float* o0 = xt + t*36;
    const float* o1 = o0 + 36;
    const float* o2 = o1 + 36;
    const float* o3 = o2 + 36;

    {
      const int j8 = p8 * 8, j4 = p8 * 4;
      float y0 = 0.f, y1 = 0.f, y2 = 0.f, y3 = 0.f;
#pragma unroll
      for (int c = 0; c < 8; c += 4) {
        float4 vv = *(const float4*)(cur + j8 + c);
        float4 h0 = *(const float4*)(Hs2 + v*65 + j8 + c);
        float4 h1 = *(const float4*)(HMs + v*68 + j8 + c);
        float4 h2 = *(const float4*)(HM2s + v*68 + j8 + c);
        float4 h3 = *(const float4*)(HM3s + v*68 + j8 + c);
        y0 += h0.x*vv.x + h0.y*vv.y + h0.z*vv.z + h0.w*vv.w;
        y1 += h1.x*vv.x + h1.y*vv.y + h1.z*vv.z + h1.w*vv.w;
        y2 += h2.x*vv.x + h2.y*vv.y + h2.z*vv.z + h2.w*vv.w;
        y3 += h3.x*vv.x + h3.y*vv.y + h3.z*vv.z + h3.w*vv.w;
      }
      {
        float4 a = *(const float4*)(HGs + v*36 + j4);
        float4 bq = *(const float4*)(HMGs + v*36 + j4);
        float4 cq = *(const float4*)(HM2Gs + v*36 + j4);
        float4 q0 = *(const float4*)(o0 + j4);
        float4 q1 = *(const float4*)(o1 + j4);
        float4 q2 = *(const float4*)(o2 + j4);
        y1 += a.x*q0.x + a.y*q0.y + a.z*q0.z + a.w*q0.w;
        y2 += bq.x*q0.x + bq.y*q0.y + bq.z*q0.z + bq.w*q0.w
            + a.x*q1.x + a.y*q1.y + a.z*q1.z + a.w*q1.w;
        y3 += cq.x*q0.x + cq.y*q0.y + cq.z*q0.z + cq.w*q0.w
            + bq.x*q1.x + bq.y*q1.y + bq.z*q1.z + bq.w*q1.w
            + a.x*q2.x + a.y*q2.y + a.z*q2.z + a.w*q2.w;
      }
#pragma unroll
      for (int off = 1; off <= 4; off <<= 1) {
        y0 += __shfl_xor(y0, off);
        y1 += __shfl_xor(y1, off);
        y2 += __shfl_xor(y2, off);
        y3 += __shfl_xor(y3, off);
      }
      if (p8 == 0) {
        yb[v*129 + t] = y0;
        if (t + 1 < TSZ) yb[v*129 + t + 1] = y1;
        if (t + 2 < TSZ) yb[v*129 + t + 2] = y2;
        if (t + 3 < TSZ) yb[v*129 + t + 3] = y3;
      }
    }

    {
      float acc = 0.0f;
      const int j0 = p4 * 16;
#pragma unroll
      for (int c = 0; c < 16; c += 4) {
        float4 mm = *(const float4*)(M4s + i*68 + j0 + c);
        float4 vv = *(const float4*)(cur + j0 + c);
        acc += mm.x*vv.x + mm.y*vv.y + mm.z*vv.z + mm.w*vv.w;
      }
      const int v0 = p4 * 8;
#pragma unroll
      for (int c = 0; c < 8; c += 4) {
        float4 g3 = *(const float4*)(M3Gs + i*36 + v0 + c);
        float4 g2 = *(const float4*)(M2Gs + i*36 + v0 + c);
        float4 g1 = *(const float4*)(MGs + i*36 + v0 + c);
        float4 g0 = *(const float4*)(Gs + i*36 + v0 + c);
        float4 q0 = *(const float4*)(o0 + v0 + c);
        float4 q1 = *(const float4*)(o1 + v0 + c);
        float4 q2 = *(const float4*)(o2 + v0 + c);
        float4 q3 = *(const float4*)(o3 + v0 + c);
        acc += g3.x*q0.x + g3.y*q0.y + g3.z*q0.z + g3.w*q0.w;
        acc += g2.x*q1.x + g2.y*q1.y + g2.z*q1.z + g2.w*q1.w;
        acc += g1.x*q2.x + g1.y*q2.y + g1.z*q2.z + g1.w*q2.w;
        acc += g0.x*q3.x + g0.y*q3.y + g0.z*q3.z + g0.w*q3.w;
      }
      acc += __shfl_xor(acc, 1);
      acc += __shfl_xor(acc, 2);
      if (p4 == 0) nxt[i] = acc;
    }
    __syncthreads();
    cb ^= 1;
  }

  for (int s = tid; s < NV*TSZ; s += 256)
    out[(size_t)b*NV*TSZ + s] = yb[(s>>7)*129 + (s&127)];
}

extern "C" void kernel_launch(void* const* d_in, const int* in_sizes, int n_in,
                              void* d_out, int out_size, void* d_ws, size_t ws_size,
                              hipStream_t stream) {
  const float* x = (const float*)d_in[0];
  const float* F = (const float*)d_in[1];
  const float* H = (const float*)d_in[2];
  const float* R = (const float*)d_in[3];
  const float* Q = (const float*)d_in[4];
  float* out = (float*)d_out;
  float* ws  = (float*)d_ws;   // ~3.06 MB used

  hipLaunchKernelGGL(kf_phase1, dim3(1), dim3(512), 0, stream, F, H, R, Q, ws);
  hipLaunchKernelGGL(kf_phase2, dim3(BSZ), dim3(256), 0, stream, x, H, ws, out);
}